// Round 1
// baseline (1096.980 us; speedup 1.0000x reference)
//
#include <hip/hip_runtime.h>
#include <math.h>

#define BM 64
#define BN 64
#define BK 16

// ---------------- tiled GEMM building blocks (f32, 64x64x16, 256 thr) ------

__device__ __forceinline__ void stage_A(const float* __restrict__ A, int lda,
                                        float As[BK][BM], int tid) {
  // A tile: 64 rows x 16 cols; element (m,k) = A[m*lda + k]; store transposed As[k][m]
  int m = tid >> 2;
  int kk = (tid & 3) << 2;
  const float4 v = *reinterpret_cast<const float4*>(A + (long long)m * lda + kk);
  As[kk + 0][m] = v.x;
  As[kk + 1][m] = v.y;
  As[kk + 2][m] = v.z;
  As[kk + 3][m] = v.w;
}

__device__ __forceinline__ void stage_B(const float* __restrict__ Bm, int ldb,
                                        float Bs[BK][BN], int tid) {
  // B tile: 16 rows x 64 cols; element (k,n) = Bm[k*ldb + n]
  int k = tid >> 4;
  int n = (tid & 15) << 2;
  const float4 v = *reinterpret_cast<const float4*>(Bm + (long long)k * ldb + n);
  *reinterpret_cast<float4*>(&Bs[k][n]) = v;
}

__device__ __forceinline__ void mma_tile(const float As[BK][BM], const float Bs[BK][BN],
                                         float acc[4][4], int tx, int ty) {
#pragma unroll
  for (int k = 0; k < BK; ++k) {
    float4 a = *reinterpret_cast<const float4*>(&As[k][ty << 2]);
    float4 b = *reinterpret_cast<const float4*>(&Bs[k][tx << 2]);
    acc[0][0] += a.x * b.x; acc[0][1] += a.x * b.y; acc[0][2] += a.x * b.z; acc[0][3] += a.x * b.w;
    acc[1][0] += a.y * b.x; acc[1][1] += a.y * b.y; acc[1][2] += a.y * b.z; acc[1][3] += a.y * b.w;
    acc[2][0] += a.z * b.x; acc[2][1] += a.z * b.y; acc[2][2] += a.z * b.z; acc[2][3] += a.z * b.w;
    acc[3][0] += a.w * b.x; acc[3][1] += a.w * b.y; acc[3][2] += a.w * b.z; acc[3][3] += a.w * b.w;
  }
}

// ---------------- generic fused GEMM ---------------------------------------
// C0 = epilogue( [A1 | A2] @ Bw )
// epilogue: (+ bscale*bias[col]) (+ addmat[row,col]) (/ denom[row]) (relu) ; optional C1 copy
__global__ __launch_bounds__(256) void gemm_k(
    const float* __restrict__ A1, int K1,
    const float* __restrict__ A2, int K2,
    int lda, long long sA,
    const float* __restrict__ Bw, int ldb, long long sB,
    const float* __restrict__ bias, float bscale,
    const float* __restrict__ addmat, int ldadd, long long sAdd,
    const float* __restrict__ denom,
    float* __restrict__ C0, int ldc0, long long sC0,
    float* __restrict__ C1, int ldc1,
    int relu) {
  __shared__ float As[BK][BM];
  __shared__ float Bs[BK][BN];
  int tid = threadIdx.x;
  int tx = tid & 15, ty = tid >> 4;
  int n0 = blockIdx.x * BN;
  int m0 = blockIdx.y * BM;
  int bz = blockIdx.z;

  const float* A1b = A1 + (long long)bz * sA + (long long)m0 * lda;
  const float* Bwb = Bw + (long long)bz * sB;
  float acc[4][4] = {};

  for (int k0 = 0; k0 < K1; k0 += BK) {
    stage_A(A1b + k0, lda, As, tid);
    stage_B(Bwb + (long long)k0 * ldb + n0, ldb, Bs, tid);
    __syncthreads();
    mma_tile(As, Bs, acc, tx, ty);
    __syncthreads();
  }
  if (A2) {
    const float* A2b = A2 + (long long)m0 * lda;
    for (int k0 = 0; k0 < K2; k0 += BK) {
      stage_A(A2b + k0, lda, As, tid);
      stage_B(Bwb + (long long)(K1 + k0) * ldb + n0, ldb, Bs, tid);
      __syncthreads();
      mma_tile(As, Bs, acc, tx, ty);
      __syncthreads();
    }
  }

  const float* addb = addmat ? addmat + (long long)bz * sAdd : nullptr;
  float* C0b = C0 + (long long)bz * sC0;
  int rbase = m0 + (ty << 2);
  int cbase = n0 + (tx << 2);
#pragma unroll
  for (int i = 0; i < 4; ++i) {
    int r = rbase + i;
    float4 v;
    v.x = acc[i][0]; v.y = acc[i][1]; v.z = acc[i][2]; v.w = acc[i][3];
    if (bias) {
      v.x += bscale * bias[cbase + 0];
      v.y += bscale * bias[cbase + 1];
      v.z += bscale * bias[cbase + 2];
      v.w += bscale * bias[cbase + 3];
    }
    if (addb) {
      float4 a4 = *reinterpret_cast<const float4*>(addb + (long long)r * ldadd + cbase);
      v.x += a4.x; v.y += a4.y; v.z += a4.z; v.w += a4.w;
    }
    if (denom) {
      float dv = denom[r];
      v.x /= dv; v.y /= dv; v.z /= dv; v.w /= dv;
    }
    if (relu) {
      v.x = fmaxf(v.x, 0.f); v.y = fmaxf(v.y, 0.f);
      v.z = fmaxf(v.z, 0.f); v.w = fmaxf(v.w, 0.f);
    }
    *reinterpret_cast<float4*>(C0b + (long long)r * ldc0 + cbase) = v;
    if (C1)
      *reinterpret_cast<float4*>(C1 + (long long)r * ldc1 + cbase) = v;
  }
}

// ---------------- scores: S[b,n,m] = q_head[n,:] . k_head[m,:]  (NT) --------
__global__ __launch_bounds__(256) void scores_nt_k(
    const float* __restrict__ q, const float* __restrict__ kmat,
    float* __restrict__ sc, int h) {
  __shared__ float As[BK][BM];
  __shared__ float Bs[BK][BN];
  int tid = threadIdx.x;
  int tx = tid & 15, ty = tid >> 4;
  int n0 = blockIdx.x * BN;  // m (column of scores)
  int m0 = blockIdx.y * BM;  // n (row of scores)
  int b = blockIdx.z;

  const float* Ab = q + ((long long)(b * 1024 + m0)) * 256 + h * 64;
  const float* Bb = kmat + ((long long)(b * 1024 + n0)) * 256 + h * 64;
  float acc[4][4] = {};
  for (int k0 = 0; k0 < 64; k0 += BK) {
    stage_A(Ab + k0, 256, As, tid);
    stage_A(Bb + k0, 256, Bs, tid);  // B transposed: same staging as A
    __syncthreads();
    mma_tile(As, Bs, acc, tx, ty);
    __syncthreads();
  }
  float* Cb = sc + (long long)b * 1024 * 1024;
  int rbase = m0 + (ty << 2);
  int cbase = n0 + (tx << 2);
#pragma unroll
  for (int i = 0; i < 4; ++i) {
    float4 v;
    v.x = acc[i][0]; v.y = acc[i][1]; v.z = acc[i][2]; v.w = acc[i][3];
    *reinterpret_cast<float4*>(Cb + (long long)(rbase + i) * 1024 + cbase) = v;
  }
}

// ---------------- z-score attention row kernel ------------------------------
__device__ __forceinline__ float block_reduce(float v, int is_max, float* red) {
#pragma unroll
  for (int o = 32; o > 0; o >>= 1) {
    float t = __shfl_down(v, o, 64);
    v = is_max ? fmaxf(v, t) : (v + t);
  }
  int lane = threadIdx.x & 63;
  int w = threadIdx.x >> 6;
  __syncthreads();
  if (lane == 0) red[w] = v;
  __syncthreads();
  float r = is_max ? fmaxf(fmaxf(red[0], red[1]), fmaxf(red[2], red[3]))
                   : (red[0] + red[1] + red[2] + red[3]);
  return r;
}

__global__ __launch_bounds__(256) void zscore_k(
    float* __restrict__ sc, const int* __restrict__ adj,
    const int* __restrict__ mask, float* __restrict__ den) {
  int n = blockIdx.x;
  int b = blockIdx.y;
  float* row = sc + ((long long)(b * 1024 + n)) * 1024;
  const int* arow = adj + ((long long)(b * 1024 + n)) * 1024;
  const int* mrow = mask + b * 1024;
  int tid = threadIdx.x;

  float4 s4 = *reinterpret_cast<const float4*>(row + tid * 4);
  int4 a4 = *reinterpret_cast<const int4*>(arow + tid * 4);
  int4 m4 = *reinterpret_cast<const int4*>(mrow + tid * 4);
  float s[4] = {s4.x, s4.y, s4.z, s4.w};
  float ad[4] = {(float)a4.x, (float)a4.y, (float)a4.z, (float)a4.w};
  int vld[4] = {m4.x == 0, m4.y == 0, m4.z == 0, m4.w == 0};

  __shared__ float red[4];

  float lc = 0.f, ls = 0.f;
#pragma unroll
  for (int u = 0; u < 4; ++u)
    if (vld[u]) { lc += 1.f; ls += s[u]; }
  float cnt = block_reduce(lc, 0, red);
  float sum = block_reduce(ls, 0, red);
  float mean = sum / (cnt + 0.0001f);

  float lq = 0.f;
#pragma unroll
  for (int u = 0; u < 4; ++u)
    if (vld[u]) { float d = s[u] - mean; lq += d * d; }
  float sq = block_reduce(lq, 0, red);
  float stdv = sqrtf(sq / (cnt + 0.0001f) + 1e-10f);

  float s2[4];
  int th[4];
#pragma unroll
  for (int u = 0; u < 4; ++u) {
    float z = (s[u] - mean) / (stdv + 0.0001f);
    float zm = vld[u] ? z : 0.f;
    th[u] = (zm < 0.f);
    s2[u] = vld[u] ? (th[u] ? -1000000000.0f : zm) : -1000000000.0f;
  }
  float lm = fmaxf(fmaxf(s2[0], s2[1]), fmaxf(s2[2], s2[3]));
  float rowmax = block_reduce(lm, 1, red);

  float e[4];
  float le = 0.f;
#pragma unroll
  for (int u = 0; u < 4; ++u) {
    e[u] = (vld[u] ? expf(s2[u] - rowmax) * ad[u] : 0.f) + 1e-10f;
    le += e[u];
  }
  float esum = block_reduce(le, 0, red);

  float w[4];
  float lw = 0.f;
#pragma unroll
  for (int u = 0; u < 4; ++u) {
    float wv = e[u] / esum;
    wv = vld[u] ? wv : 0.f;
    int kill = (!vld[u]) || th[u] || (ad[u] == 0.f);
    w[u] = kill ? 0.f : wv;
    lw += w[u];
  }
  float wsum = block_reduce(lw, 0, red);

  float4 o;
  o.x = w[0]; o.y = w[1]; o.z = w[2]; o.w = w[3];
  *reinterpret_cast<float4*>(row + tid * 4) = o;
  if (tid == 0) den[b * 1024 + n] = wsum + 1.0f;
}

// ---------------- launch -----------------------------------------------------
extern "C" void kernel_launch(void* const* d_in, const int* in_sizes, int n_in,
                              void* d_out, int out_size, void* d_ws, size_t ws_size,
                              hipStream_t stream) {
  const float* X = (const float*)d_in[0];      // gcn_inputs [4,1024,256]
  const float* R = (const float*)d_in[1];      // rel_embs
  const int* adj = (const int*)d_in[2];        // [4,1024,1024]
  const int* mask = (const int*)d_in[3];       // [4,1,1024]
  const float* W_Q = (const float*)d_in[4];    // [512,256]
  const float* b_Q = (const float*)d_in[5];
  const float* W_K = (const float*)d_in[6];    // [256,256]
  const float* b_K = (const float*)d_in[7];
  const float* W_gcn = (const float*)d_in[8];  // [8,256,256]
  const float* b_gcn = (const float*)d_in[9];  // [8,256]
  const float* W_out = (const float*)d_in[10]; // [2048,256]
  const float* b_out = (const float*)d_in[11];
  float* out = (float*)d_out;

  float* ws = (float*)d_ws;
  float* q  = ws;                 // 1M floats
  float* kb = q + (1 << 20);      // 1M
  float* sc = kb + (1 << 20);     // 4M (one head: B*N*N)
  float* den = sc + (4 << 20);    // 4096 (+pad)
  float* Tb = den + 8192;         // 1M
  float* ob = Tb + (1 << 20);     // 1M
  float* ob2 = ob + (1 << 20);    // 1M
  float* fin = ob2 + (1 << 20);   // 8M  (B*N*2048)

  // q = [X|R] @ W_Q + b_Q   (M=4096, K=512, N=256)
  gemm_k<<<dim3(4, 64, 1), 256, 0, stream>>>(
      X, 256, R, 256, 256, 0LL,
      W_Q, 256, 0LL,
      b_Q, 1.0f,
      nullptr, 0, 0LL,
      nullptr,
      q, 256, 0LL,
      nullptr, 0, 0);
  // k = X @ W_K + b_K
  gemm_k<<<dim3(4, 64, 1), 256, 0, stream>>>(
      X, 256, nullptr, 0, 256, 0LL,
      W_K, 256, 0LL,
      b_K, 1.0f,
      nullptr, 0, 0LL,
      nullptr,
      kb, 256, 0LL,
      nullptr, 0, 0);

  for (int h = 0; h < 4; ++h) {
    scores_nt_k<<<dim3(16, 16, 4), 256, 0, stream>>>(q, kb, sc, h);
    zscore_k<<<dim3(1024, 4), 256, 0, stream>>>(sc, adj, mask, den);
    for (int l = 0; l < 2; ++l) {
      int idx = h * 2 + l;
      const float* src = l ? ob : X;
      float* dst = l ? ob2 : ob;
      // T = a @ src + src   (per batch; M=1024, K=1024, N=256)
      gemm_k<<<dim3(4, 16, 4), 256, 0, stream>>>(
          sc, 1024, nullptr, 0, 1024, 1048576LL,
          src, 256, 262144LL,
          nullptr, 0.f,
          src, 256, 262144LL,
          nullptr,
          Tb, 256, 262144LL,
          nullptr, 0, 0);
      // dst = relu((T @ W_gcn[idx] + 2*b_gcn[idx]) / denom); also -> fin[:, idx*256:]
      gemm_k<<<dim3(4, 64, 1), 256, 0, stream>>>(
          Tb, 256, nullptr, 0, 256, 0LL,
          W_gcn + (long long)idx * 65536, 256, 0LL,
          b_gcn + idx * 256, 2.0f,
          nullptr, 0, 0LL,
          den,
          dst, 256, 0LL,
          fin + idx * 256, 2048,
          1);
    }
  }

  // out = X + fin @ W_out + b_out   (M=4096, K=2048, N=256)
  gemm_k<<<dim3(4, 64, 1), 256, 0, stream>>>(
      fin, 2048, nullptr, 0, 2048, 0LL,
      W_out, 256, 0LL,
      b_out, 1.0f,
      X, 256, 0LL,
      nullptr,
      out, 256, 0LL,
      nullptr, 0, 0);
}

// Round 2
// 721.205 us; speedup vs baseline: 1.5210x; 1.5210x over previous
//
#include <hip/hip_runtime.h>
#include <math.h>

#define BM 64
#define BN 64
#define BK 16
#define LS 68  // padded LDS row stride (+4 kills 4-way staging bank conflicts)

__device__ __forceinline__ float bf2f(unsigned short u) {
  union { unsigned int i; float f; } v; v.i = ((unsigned int)u) << 16; return v.f;
}
__device__ __forceinline__ unsigned short f2bf(float f) {
  union { float f; unsigned int i; } v; v.f = f;
  unsigned int x = v.i;
  return (unsigned short)((x + 0x7FFFu + ((x >> 16) & 1u)) >> 16);
}

// ---------------- tiled GEMM building blocks (f32 compute, 64x64x16) --------

__device__ __forceinline__ void stage_Af(const float* __restrict__ A, int lda,
                                         float As[BK][LS], int tid) {
  int m = tid >> 2, kk = (tid & 3) << 2;
  const float4 v = *reinterpret_cast<const float4*>(A + (long long)m * lda + kk);
  As[kk + 0][m] = v.x; As[kk + 1][m] = v.y;
  As[kk + 2][m] = v.z; As[kk + 3][m] = v.w;
}

__device__ __forceinline__ void stage_Abf(const unsigned short* __restrict__ A, int lda,
                                          float As[BK][LS], int tid) {
  int m = tid >> 2, kk = (tid & 3) << 2;
  const ushort4 u = *reinterpret_cast<const ushort4*>(A + (long long)m * lda + kk);
  As[kk + 0][m] = bf2f(u.x); As[kk + 1][m] = bf2f(u.y);
  As[kk + 2][m] = bf2f(u.z); As[kk + 3][m] = bf2f(u.w);
}

__device__ __forceinline__ void stage_B(const float* __restrict__ Bm, int ldb,
                                        float Bs[BK][LS], int tid) {
  int k = tid >> 4, n = (tid & 15) << 2;
  *reinterpret_cast<float4*>(&Bs[k][n]) =
      *reinterpret_cast<const float4*>(Bm + (long long)k * ldb + n);
}

__device__ __forceinline__ void mma_tile(const float As[BK][LS], const float Bs[BK][LS],
                                         float acc[4][4], int tx, int ty) {
#pragma unroll
  for (int k = 0; k < BK; ++k) {
    float4 a = *reinterpret_cast<const float4*>(&As[k][ty << 2]);
    float4 b = *reinterpret_cast<const float4*>(&Bs[k][tx << 2]);
    acc[0][0] += a.x * b.x; acc[0][1] += a.x * b.y; acc[0][2] += a.x * b.z; acc[0][3] += a.x * b.w;
    acc[1][0] += a.y * b.x; acc[1][1] += a.y * b.y; acc[1][2] += a.y * b.z; acc[1][3] += a.y * b.w;
    acc[2][0] += a.z * b.x; acc[2][1] += a.z * b.y; acc[2][2] += a.z * b.z; acc[2][3] += a.z * b.w;
    acc[3][0] += a.w * b.x; acc[3][1] += a.w * b.y; acc[3][2] += a.w * b.z; acc[3][3] += a.w * b.w;
  }
}

// ---------------- generic f32 GEMM: C = [A1|A2] @ B (+bias) (+addmat) ------
__global__ __launch_bounds__(256) void gemm_k(
    const float* __restrict__ A1, int K1,
    const float* __restrict__ A2, int K2, int lda,
    const float* __restrict__ Bw, int ldb,
    const float* __restrict__ bias, float bscale,
    const float* __restrict__ addmat, int ldadd,
    float* __restrict__ C0, int ldc0) {
  __shared__ float As[BK][LS];
  __shared__ float Bs[BK][LS];
  int tid = threadIdx.x, tx = tid & 15, ty = tid >> 4;
  int n0 = blockIdx.x * BN, m0 = blockIdx.y * BM;

  const float* A1b = A1 + (long long)m0 * lda;
  float acc[4][4] = {};
  for (int k0 = 0; k0 < K1; k0 += BK) {
    stage_Af(A1b + k0, lda, As, tid);
    stage_B(Bw + (long long)k0 * ldb + n0, ldb, Bs, tid);
    __syncthreads();
    mma_tile(As, Bs, acc, tx, ty);
    __syncthreads();
  }
  if (A2) {
    const float* A2b = A2 + (long long)m0 * lda;
    for (int k0 = 0; k0 < K2; k0 += BK) {
      stage_Af(A2b + k0, lda, As, tid);
      stage_B(Bw + (long long)(K1 + k0) * ldb + n0, ldb, Bs, tid);
      __syncthreads();
      mma_tile(As, Bs, acc, tx, ty);
      __syncthreads();
    }
  }
  int rbase = m0 + (ty << 2), cbase = n0 + (tx << 2);
#pragma unroll
  for (int i = 0; i < 4; ++i) {
    int r = rbase + i;
    float4 v = {acc[i][0], acc[i][1], acc[i][2], acc[i][3]};
    if (bias) {
      v.x += bscale * bias[cbase + 0]; v.y += bscale * bias[cbase + 1];
      v.z += bscale * bias[cbase + 2]; v.w += bscale * bias[cbase + 3];
    }
    if (addmat) {
      float4 a4 = *reinterpret_cast<const float4*>(addmat + (long long)r * ldadd + cbase);
      v.x += a4.x; v.y += a4.y; v.z += a4.z; v.w += a4.w;
    }
    *reinterpret_cast<float4*>(C0 + (long long)r * ldc0 + cbase) = v;
  }
}

// ---------------- scores: S[b,n,m] = q_head[n,:] . k_head[m,:]  (NT) --------
__global__ __launch_bounds__(256) void scores_nt_k(
    const float* __restrict__ q, const float* __restrict__ kmat,
    float* __restrict__ sc, int h) {
  __shared__ float As[BK][LS];
  __shared__ float Bs[BK][LS];
  int tid = threadIdx.x, tx = tid & 15, ty = tid >> 4;
  int n0 = blockIdx.x * BN, m0 = blockIdx.y * BM, b = blockIdx.z;

  const float* Ab = q + ((long long)(b * 1024 + m0)) * 256 + h * 64;
  const float* Bb = kmat + ((long long)(b * 1024 + n0)) * 256 + h * 64;
  float acc[4][4] = {};
  for (int k0 = 0; k0 < 64; k0 += BK) {
    stage_Af(Ab + k0, 256, As, tid);
    stage_Af(Bb + k0, 256, Bs, tid);  // B^T: same transpose staging
    __syncthreads();
    mma_tile(As, Bs, acc, tx, ty);
    __syncthreads();
  }
  float* Cb = sc + (long long)b * 1048576;
  int rbase = m0 + (ty << 2), cbase = n0 + (tx << 2);
#pragma unroll
  for (int i = 0; i < 4; ++i) {
    float4 v = {acc[i][0], acc[i][1], acc[i][2], acc[i][3]};
    *reinterpret_cast<float4*>(Cb + (long long)(rbase + i) * 1024 + cbase) = v;
  }
}

// ---------------- z-score attention row kernel → bf16 weights ---------------
__device__ __forceinline__ float block_reduce(float v, int is_max, float* red) {
#pragma unroll
  for (int o = 32; o > 0; o >>= 1) {
    float t = __shfl_down(v, o, 64);
    v = is_max ? fmaxf(v, t) : (v + t);
  }
  int lane = threadIdx.x & 63, w = threadIdx.x >> 6;
  __syncthreads();
  if (lane == 0) red[w] = v;
  __syncthreads();
  return is_max ? fmaxf(fmaxf(red[0], red[1]), fmaxf(red[2], red[3]))
                : (red[0] + red[1] + red[2] + red[3]);
}

__global__ __launch_bounds__(256) void zscore_k(
    const float* __restrict__ sc, const int* __restrict__ adj,
    const int* __restrict__ mask, unsigned short* __restrict__ wout,
    float* __restrict__ denh) {
  int n = blockIdx.x, b = blockIdx.y;
  const float* row = sc + ((long long)(b * 1024 + n)) * 1024;
  const int* arow = adj + ((long long)(b * 1024 + n)) * 1024;
  const int* mrow = mask + b * 1024;
  int tid = threadIdx.x;

  float4 s4 = *reinterpret_cast<const float4*>(row + tid * 4);
  int4 a4 = *reinterpret_cast<const int4*>(arow + tid * 4);
  int4 m4 = *reinterpret_cast<const int4*>(mrow + tid * 4);
  float s[4] = {s4.x, s4.y, s4.z, s4.w};
  float ad[4] = {(float)a4.x, (float)a4.y, (float)a4.z, (float)a4.w};
  int vld[4] = {m4.x == 0, m4.y == 0, m4.z == 0, m4.w == 0};

  __shared__ float red[4];

  float lc = 0.f, ls = 0.f;
#pragma unroll
  for (int u = 0; u < 4; ++u)
    if (vld[u]) { lc += 1.f; ls += s[u]; }
  float cnt = block_reduce(lc, 0, red);
  float sum = block_reduce(ls, 0, red);
  float mean = sum / (cnt + 0.0001f);

  float lq = 0.f;
#pragma unroll
  for (int u = 0; u < 4; ++u)
    if (vld[u]) { float d = s[u] - mean; lq += d * d; }
  float sq = block_reduce(lq, 0, red);
  float stdv = sqrtf(sq / (cnt + 0.0001f) + 1e-10f);

  float s2[4];
  int th[4];
#pragma unroll
  for (int u = 0; u < 4; ++u) {
    float z = (s[u] - mean) / (stdv + 0.0001f);
    float zm = vld[u] ? z : 0.f;
    th[u] = (zm < 0.f);
    s2[u] = vld[u] ? (th[u] ? -1000000000.0f : zm) : -1000000000.0f;
  }
  float lm = fmaxf(fmaxf(s2[0], s2[1]), fmaxf(s2[2], s2[3]));
  float rowmax = block_reduce(lm, 1, red);

  float e[4];
  float le = 0.f;
#pragma unroll
  for (int u = 0; u < 4; ++u) {
    e[u] = (vld[u] ? expf(s2[u] - rowmax) * ad[u] : 0.f) + 1e-10f;
    le += e[u];
  }
  float esum = block_reduce(le, 0, red);

  float w[4];
  float lw = 0.f;
#pragma unroll
  for (int u = 0; u < 4; ++u) {
    float wv = e[u] / esum;
    wv = vld[u] ? wv : 0.f;
    int kill = (!vld[u]) || th[u] || (ad[u] == 0.f);
    w[u] = kill ? 0.f : wv;
    lw += w[u];
  }
  float wsum = block_reduce(lw, 0, red);

  ushort4 o = {f2bf(w[0]), f2bf(w[1]), f2bf(w[2]), f2bf(w[3])};
  *reinterpret_cast<ushort4*>(wout + ((size_t)b << 20) + (size_t)n * 1024 + tid * 4) = o;
  if (tid == 0) denh[b * 1024 + n] = wsum + 1.0f;
}

// ---------------- batched T = a(bf16) @ src + src, z = h*4+b ----------------
__global__ __launch_bounds__(256) void gemm_ax_k(
    const unsigned short* __restrict__ Wt,  // [16][1024][1024] bf16
    const float* __restrict__ src, int bmask,
    float* __restrict__ T) {
  __shared__ float As[BK][LS];
  __shared__ float Bs[BK][LS];
  int tid = threadIdx.x, tx = tid & 15, ty = tid >> 4;
  int n0 = blockIdx.x * BN, m0 = blockIdx.y * BM, g = blockIdx.z;

  const unsigned short* Ab = Wt + ((long long)g << 20) + (long long)m0 * 1024;
  const float* Bb = src + (long long)(g & bmask) * 262144;
  float acc[4][4] = {};
  for (int k0 = 0; k0 < 1024; k0 += BK) {
    stage_Abf(Ab + k0, 1024, As, tid);
    stage_B(Bb + (long long)k0 * 256 + n0, 256, Bs, tid);
    __syncthreads();
    mma_tile(As, Bs, acc, tx, ty);
    __syncthreads();
  }
  float* Tg = T + (long long)g * 262144;
  int rbase = m0 + (ty << 2), cbase = n0 + (tx << 2);
#pragma unroll
  for (int i = 0; i < 4; ++i) {
    int r = rbase + i;
    float4 a4 = *reinterpret_cast<const float4*>(Bb + (long long)r * 256 + cbase);
    float4 v = {acc[i][0] + a4.x, acc[i][1] + a4.y, acc[i][2] + a4.z, acc[i][3] + a4.w};
    *reinterpret_cast<float4*>(Tg + (long long)r * 256 + cbase) = v;
  }
}

// ---------------- batched dst = relu((T@W[idx] + 2b[idx]) / den) ------------
__global__ __launch_bounds__(256) void gemm_xw_k(
    const float* __restrict__ T, const float* __restrict__ Wg,
    const float* __restrict__ bg, const float* __restrict__ den,
    int l, float* __restrict__ ob, float* __restrict__ fin) {
  __shared__ float As[BK][LS];
  __shared__ float Bs[BK][LS];
  int tid = threadIdx.x, tx = tid & 15, ty = tid >> 4;
  int n0 = blockIdx.x * BN, m0 = blockIdx.y * BM, g = blockIdx.z;
  int h = g >> 2, b = g & 3, idx = h * 2 + l;

  const float* Ab = T + (long long)g * 262144 + (long long)m0 * 256;
  const float* Bw = Wg + (long long)idx * 65536;
  float acc[4][4] = {};
  for (int k0 = 0; k0 < 256; k0 += BK) {
    stage_Af(Ab + k0, 256, As, tid);
    stage_B(Bw + (long long)k0 * 256 + n0, 256, Bs, tid);
    __syncthreads();
    mma_tile(As, Bs, acc, tx, ty);
    __syncthreads();
  }
  const float* bb = bg + idx * 256;
  int rbase = m0 + (ty << 2), cbase = n0 + (tx << 2);
#pragma unroll
  for (int i = 0; i < 4; ++i) {
    int r = rbase + i;
    float dv = den[g * 1024 + r];
    float4 v = {acc[i][0] + 2.f * bb[cbase + 0], acc[i][1] + 2.f * bb[cbase + 1],
                acc[i][2] + 2.f * bb[cbase + 2], acc[i][3] + 2.f * bb[cbase + 3]};
    v.x = fmaxf(v.x / dv, 0.f); v.y = fmaxf(v.y / dv, 0.f);
    v.z = fmaxf(v.z / dv, 0.f); v.w = fmaxf(v.w / dv, 0.f);
    *reinterpret_cast<float4*>(fin + (long long)b * 2097152 + (long long)r * 2048 +
                               idx * 256 + cbase) = v;
    if (ob)
      *reinterpret_cast<float4*>(ob + (long long)g * 262144 + (long long)r * 256 + cbase) = v;
  }
}

// ---------------- launch -----------------------------------------------------
extern "C" void kernel_launch(void* const* d_in, const int* in_sizes, int n_in,
                              void* d_out, int out_size, void* d_ws, size_t ws_size,
                              hipStream_t stream) {
  const float* X = (const float*)d_in[0];
  const float* R = (const float*)d_in[1];
  const int* adj = (const int*)d_in[2];
  const int* mask = (const int*)d_in[3];
  const float* W_Q = (const float*)d_in[4];
  const float* b_Q = (const float*)d_in[5];
  const float* W_K = (const float*)d_in[6];
  const float* b_K = (const float*)d_in[7];
  const float* W_gcn = (const float*)d_in[8];
  const float* b_gcn = (const float*)d_in[9];
  const float* W_out = (const float*)d_in[10];
  const float* b_out = (const float*)d_in[11];
  float* out = (float*)d_out;

  float* ws = (float*)d_ws;
  float* q = ws;                                           // 1M f32
  float* kb = ws + (1 << 20);                              // 1M
  float* sc = ws + (2 << 20);                              // 4M f32 (reused as Tb)
  unsigned short* wght = (unsigned short*)(ws + (6 << 20)); // 16M bf16 (8M f32 span)
  float* den = ws + (14 << 20);                            // 16K
  float* ob = ws + (14 << 20) + 16384;                     // 4M
  float* fin = ob + (4 << 20);                             // 8M
  float* Tb = sc;

  // q = [X|R] @ W_Q + b_Q ; k = X @ W_K + b_K
  gemm_k<<<dim3(4, 64, 1), 256, 0, stream>>>(X, 256, R, 256, 256, W_Q, 256,
                                             b_Q, 1.f, nullptr, 0, q, 256);
  gemm_k<<<dim3(4, 64, 1), 256, 0, stream>>>(X, 256, nullptr, 0, 256, W_K, 256,
                                             b_K, 1.f, nullptr, 0, kb, 256);

  for (int h = 0; h < 4; ++h) {
    scores_nt_k<<<dim3(16, 16, 4), 256, 0, stream>>>(q, kb, sc, h);
    zscore_k<<<dim3(1024, 4), 256, 0, stream>>>(
        sc, adj, mask, wght + ((size_t)h << 22), den + h * 4096);
  }

  // layer 0: T = a@X + X ; ob = relu((T@W+2b)/den) (also into fin)
  gemm_ax_k<<<dim3(4, 16, 16), 256, 0, stream>>>(wght, X, 3, Tb);
  gemm_xw_k<<<dim3(4, 16, 16), 256, 0, stream>>>(Tb, W_gcn, b_gcn, den, 0, ob, fin);
  // layer 1: T = a@ob + ob ; fin slice = relu((T@W+2b)/den)
  gemm_ax_k<<<dim3(4, 16, 16), 256, 0, stream>>>(wght, ob, 15, Tb);
  gemm_xw_k<<<dim3(4, 16, 16), 256, 0, stream>>>(Tb, W_gcn, b_gcn, den, 1, nullptr, fin);

  // out = X + fin @ W_out + b_out
  gemm_k<<<dim3(4, 64, 1), 256, 0, stream>>>(fin, 2048, nullptr, 0, 2048, W_out, 256,
                                             b_out, 1.f, X, 256, out, 256);
}

// Round 3
// 379.618 us; speedup vs baseline: 2.8897x; 1.8998x over previous
//
#include <hip/hip_runtime.h>
#include <math.h>

typedef unsigned short u16;
typedef __attribute__((ext_vector_type(8))) short short8;
typedef __attribute__((ext_vector_type(4))) float floatx4;

#define LDS_P 72  // LDS row stride (elems); +8 pad keeps ds_read_b128 2-way max

__device__ __forceinline__ float bf2f(u16 u) {
  union { unsigned int i; float f; } v; v.i = ((unsigned int)u) << 16; return v.f;
}
__device__ __forceinline__ u16 f2bf(float f) {
  union { float f; unsigned int i; } v; v.f = f;
  unsigned int x = v.i;
  return (u16)((x + 0x7FFFu + ((x >> 16) & 1u)) >> 16);
}

// ---- stage a 64x64 bf16 tile (row-major, ldg elems) into LDS [64][LDS_P] ----
__device__ __forceinline__ void stage64(const u16* __restrict__ G, int ldg,
                                        u16* __restrict__ S, int tid) {
#pragma unroll
  for (int j = 0; j < 2; ++j) {
    int id = tid + (j << 8);
    int row = id >> 3, c8 = (id & 7) << 3;
    *reinterpret_cast<float4*>(S + row * LDS_P + c8) =
        *reinterpret_cast<const float4*>(G + (long long)row * ldg + c8);
  }
}

// ---- core: 64x64 block tile, 4 waves each 32x32 (2x2 MFMA 16x16x32) --------
__device__ __forceinline__ void mfma_loop(const u16* __restrict__ A, int lda,
                                          const u16* __restrict__ Bt, int ldb,
                                          int K, u16* As, u16* Bs,
                                          floatx4 acc[2][2], int tid) {
  int lane = tid & 63;
  int wm = ((tid >> 6) & 1) << 5, wn = ((tid >> 6) >> 1) << 5;
  int lr = lane & 15, lq8 = (lane >> 4) << 3;
  for (int k0 = 0; k0 < K; k0 += 64) {
    stage64(A + k0, lda, As, tid);
    stage64(Bt + k0, ldb, Bs, tid);
    __syncthreads();
#pragma unroll
    for (int kc = 0; kc < 64; kc += 32) {
      short8 a0 = *reinterpret_cast<const short8*>(As + (wm + lr) * LDS_P + kc + lq8);
      short8 a1 = *reinterpret_cast<const short8*>(As + (wm + 16 + lr) * LDS_P + kc + lq8);
      short8 b0 = *reinterpret_cast<const short8*>(Bs + (wn + lr) * LDS_P + kc + lq8);
      short8 b1 = *reinterpret_cast<const short8*>(Bs + (wn + 16 + lr) * LDS_P + kc + lq8);
      acc[0][0] = __builtin_amdgcn_mfma_f32_16x16x32_bf16(a0, b0, acc[0][0], 0, 0, 0);
      acc[0][1] = __builtin_amdgcn_mfma_f32_16x16x32_bf16(a0, b1, acc[0][1], 0, 0, 0);
      acc[1][0] = __builtin_amdgcn_mfma_f32_16x16x32_bf16(a1, b0, acc[1][0], 0, 0, 0);
      acc[1][1] = __builtin_amdgcn_mfma_f32_16x16x32_bf16(a1, b1, acc[1][1], 0, 0, 0);
    }
    __syncthreads();
  }
}

#define EPI_SETUP                                                     \
  int lane = threadIdx.x & 63;                                        \
  int wm = ((threadIdx.x >> 6) & 1) << 5,                             \
      wn = ((threadIdx.x >> 6) >> 1) << 5;                            \
  int lr = lane & 15, lq4 = (lane >> 4) << 2;

// ---- q/k projection: C(bf16) = A(bf16) @ Bt^T + bias ----------------------
__global__ __launch_bounds__(256) void proj_k(
    const u16* __restrict__ A, const u16* __restrict__ Bt,
    const float* __restrict__ bias, u16* __restrict__ C,
    int K, int lda, int ldb, int ldc) {
  __shared__ u16 As[64 * LDS_P], Bs[64 * LDS_P];
  int m0 = blockIdx.y << 6, n0 = blockIdx.x << 6;
  floatx4 acc[2][2] = {};
  mfma_loop(A + (long long)m0 * lda, lda, Bt + (long long)n0 * ldb, ldb, K, As, Bs,
            acc, threadIdx.x);
  EPI_SETUP
#pragma unroll
  for (int ti = 0; ti < 2; ++ti)
#pragma unroll
    for (int tj = 0; tj < 2; ++tj)
#pragma unroll
      for (int r = 0; r < 4; ++r) {
        int row = m0 + wm + ti * 16 + lq4 + r;
        int col = n0 + wn + tj * 16 + lr;
        C[(long long)row * ldc + col] = f2bf(acc[ti][tj][r] + bias[col]);
      }
}

// ---- scores: sc(f32)[b][n][m] = q_h[n,:].k_h[m,:] --------------------------
__global__ __launch_bounds__(256) void mscore_k(
    const u16* __restrict__ q, const u16* __restrict__ kb,
    float* __restrict__ sc, int h) {
  __shared__ u16 As[64 * LDS_P], Bs[64 * LDS_P];
  int b = blockIdx.z;
  int m0 = blockIdx.y << 6, n0 = blockIdx.x << 6;
  const u16* Ab = q + b * 262144 + h * 64;
  const u16* Bb = kb + b * 262144 + h * 64;
  floatx4 acc[2][2] = {};
  mfma_loop(Ab + (long long)m0 * 256, 256, Bb + (long long)n0 * 256, 256, 64, As, Bs,
            acc, threadIdx.x);
  float* Cb = sc + (long long)b * 1048576;
  EPI_SETUP
#pragma unroll
  for (int ti = 0; ti < 2; ++ti)
#pragma unroll
    for (int tj = 0; tj < 2; ++tj)
#pragma unroll
      for (int r = 0; r < 4; ++r) {
        int row = m0 + wm + ti * 16 + lq4 + r;
        int col = n0 + wn + tj * 16 + lr;
        Cb[(long long)row * 1024 + col] = acc[ti][tj][r];
      }
}

// ---- T(bf16) = wght(bf16) @ srcT^T + src  (z = h*4+b) ----------------------
__global__ __launch_bounds__(256) void max_k(
    const u16* __restrict__ wght, const u16* __restrict__ srcT,
    const u16* __restrict__ addsrc, int zmask, int ldadd, long long sAdd,
    u16* __restrict__ T) {
  __shared__ u16 As[64 * LDS_P], Bs[64 * LDS_P];
  int z = blockIdx.z;
  int m0 = blockIdx.y << 6, n0 = blockIdx.x << 6;
  const u16* Ab = wght + ((long long)z << 20);
  const u16* Bb = srcT + (long long)(z & zmask) * 262144;
  const u16* addb = addsrc + (long long)(z & zmask) * sAdd;
  floatx4 acc[2][2] = {};
  mfma_loop(Ab + (long long)m0 * 1024, 1024, Bb + (long long)n0 * 1024, 1024, 1024,
            As, Bs, acc, threadIdx.x);
  u16* Tb = T + ((long long)z << 18);
  EPI_SETUP
#pragma unroll
  for (int ti = 0; ti < 2; ++ti)
#pragma unroll
    for (int tj = 0; tj < 2; ++tj)
#pragma unroll
      for (int r = 0; r < 4; ++r) {
        int row = m0 + wm + ti * 16 + lq4 + r;
        int col = n0 + wn + tj * 16 + lr;
        float v = acc[ti][tj][r] + bf2f(addb[(long long)row * ldadd + col]);
        Tb[(long long)row * 256 + col] = f2bf(v);
      }
}

// ---- layer GEMM: relu((T @ Wg^T + 2b)/den) -> fin slice (+ob) --------------
__global__ __launch_bounds__(256) void mxw_k(
    const u16* __restrict__ T, const u16* __restrict__ WgT,
    const float* __restrict__ bg, const float* __restrict__ den,
    u16* __restrict__ ob, u16* __restrict__ fin) {
  __shared__ u16 As[64 * LDS_P], Bs[64 * LDS_P];
  int z = blockIdx.z;
  int m0 = blockIdx.y << 6, n0 = blockIdx.x << 6;
  const u16* Ab = T + ((long long)z << 18);
  const u16* Bb = WgT + (long long)(z >> 2) * 131072;
  const float* bb = bg + (z >> 2) * 512;
  const float* dn = den + z * 1024;
  floatx4 acc[2][2] = {};
  mfma_loop(Ab + (long long)m0 * 256, 256, Bb + (long long)n0 * 256, 256, 256,
            As, Bs, acc, threadIdx.x);
  EPI_SETUP
#pragma unroll
  for (int ti = 0; ti < 2; ++ti)
#pragma unroll
    for (int tj = 0; tj < 2; ++tj)
#pragma unroll
      for (int r = 0; r < 4; ++r) {
        int row = m0 + wm + ti * 16 + lq4 + r;
        int col = n0 + wn + tj * 16 + lr;
        float v = (acc[ti][tj][r] + 2.f * bb[col]) / dn[row];
        v = fmaxf(v, 0.f);
        u16 bv = f2bf(v);
        fin[(long long)(z & 3) * 2097152 + (long long)row * 2048 + (z >> 2) * 512 + col] = bv;
        if (ob) ob[((long long)z << 18) + (long long)row * 256 + col] = bv;
      }
}

// ---- final: out(f32) = X + fin @ Wo^T + b ---------------------------------
__global__ __launch_bounds__(256) void mfinal_k(
    const u16* __restrict__ fin, const u16* __restrict__ WoT,
    const float* __restrict__ bias, const float* __restrict__ X,
    float* __restrict__ out) {
  __shared__ u16 As[64 * LDS_P], Bs[64 * LDS_P];
  int m0 = blockIdx.y << 6, n0 = blockIdx.x << 6;
  floatx4 acc[2][2] = {};
  mfma_loop(fin + (long long)m0 * 2048, 2048, WoT + (long long)n0 * 2048, 2048, 2048,
            As, Bs, acc, threadIdx.x);
  EPI_SETUP
#pragma unroll
  for (int ti = 0; ti < 2; ++ti)
#pragma unroll
    for (int tj = 0; tj < 2; ++tj)
#pragma unroll
      for (int r = 0; r < 4; ++r) {
        int row = m0 + wm + ti * 16 + lq4 + r;
        int col = n0 + wn + tj * 16 + lr;
        out[(long long)row * 256 + col] =
            acc[ti][tj][r] + bias[col] + X[(long long)row * 256 + col];
      }
}

// ---- prep: [X|R] concat -> bf16 -------------------------------------------
__global__ __launch_bounds__(256) void concat_k(const float* __restrict__ X,
                                                const float* __restrict__ R,
                                                u16* __restrict__ A) {
  int idx = blockIdx.x * 256 + threadIdx.x;
  int col = idx & 511, row = idx >> 9;
  float v = (col < 256) ? X[row * 256 + col] : R[row * 256 + col - 256];
  A[idx] = f2bf(v);
}

// ---- prep: transpose+convert f32 [Z][I][256] -> bf16 [Z][256][I] -----------
__global__ __launch_bounds__(256) void tconv_k(const float* __restrict__ src,
                                               u16* __restrict__ dst, int I) {
  int z = blockIdx.y;
  int idx = (blockIdx.x << 8) + threadIdx.x;
  int i = idx >> 8, j = idx & 255;
  long long base = (long long)z * I * 256;
  dst[base + (long long)j * I + i] = f2bf(src[base + idx]);
}

// ---- prep: transpose bf16 [Z][I][256] -> bf16 [Z][256][I] ------------------
__global__ __launch_bounds__(256) void tbf_k(const u16* __restrict__ src,
                                             u16* __restrict__ dst, int I) {
  int z = blockIdx.y;
  int idx = (blockIdx.x << 8) + threadIdx.x;
  int i = idx >> 8, j = idx & 255;
  long long base = (long long)z * I * 256;
  dst[base + (long long)j * I + i] = src[base + idx];
}

// ---- z-score attention row kernel -> bf16 weights --------------------------
__device__ __forceinline__ float block_reduce(float v, int is_max, float* red) {
#pragma unroll
  for (int o = 32; o > 0; o >>= 1) {
    float t = __shfl_down(v, o, 64);
    v = is_max ? fmaxf(v, t) : (v + t);
  }
  int lane = threadIdx.x & 63, w = threadIdx.x >> 6;
  __syncthreads();
  if (lane == 0) red[w] = v;
  __syncthreads();
  return is_max ? fmaxf(fmaxf(red[0], red[1]), fmaxf(red[2], red[3]))
                : (red[0] + red[1] + red[2] + red[3]);
}

__global__ __launch_bounds__(256) void zscore_k(
    const float* __restrict__ sc, const int* __restrict__ adj,
    const int* __restrict__ mask, u16* __restrict__ wout,
    float* __restrict__ denh) {
  int n = blockIdx.x, b = blockIdx.y;
  const float* row = sc + ((long long)(b * 1024 + n)) * 1024;
  const int* arow = adj + ((long long)(b * 1024 + n)) * 1024;
  const int* mrow = mask + b * 1024;
  int tid = threadIdx.x;

  float4 s4 = *reinterpret_cast<const float4*>(row + tid * 4);
  int4 a4 = *reinterpret_cast<const int4*>(arow + tid * 4);
  int4 m4 = *reinterpret_cast<const int4*>(mrow + tid * 4);
  float s[4] = {s4.x, s4.y, s4.z, s4.w};
  float ad[4] = {(float)a4.x, (float)a4.y, (float)a4.z, (float)a4.w};
  int vld[4] = {m4.x == 0, m4.y == 0, m4.z == 0, m4.w == 0};

  __shared__ float red[4];

  float lc = 0.f, ls = 0.f;
#pragma unroll
  for (int u = 0; u < 4; ++u)
    if (vld[u]) { lc += 1.f; ls += s[u]; }
  float cnt = block_reduce(lc, 0, red);
  float sum = block_reduce(ls, 0, red);
  float mean = sum / (cnt + 0.0001f);

  float lq = 0.f;
#pragma unroll
  for (int u = 0; u < 4; ++u)
    if (vld[u]) { float d = s[u] - mean; lq += d * d; }
  float sq = block_reduce(lq, 0, red);
  float stdv = sqrtf(sq / (cnt + 0.0001f) + 1e-10f);

  float s2[4];
  int th[4];
#pragma unroll
  for (int u = 0; u < 4; ++u) {
    float z = (s[u] - mean) / (stdv + 0.0001f);
    float zm = vld[u] ? z : 0.f;
    th[u] = (zm < 0.f);
    s2[u] = vld[u] ? (th[u] ? -1000000000.0f : zm) : -1000000000.0f;
  }
  float lm = fmaxf(fmaxf(s2[0], s2[1]), fmaxf(s2[2], s2[3]));
  float rowmax = block_reduce(lm, 1, red);

  float e[4];
  float le = 0.f;
#pragma unroll
  for (int u = 0; u < 4; ++u) {
    e[u] = (vld[u] ? expf(s2[u] - rowmax) * ad[u] : 0.f) + 1e-10f;
    le += e[u];
  }
  float esum = block_reduce(le, 0, red);

  float w[4];
  float lw = 0.f;
#pragma unroll
  for (int u = 0; u < 4; ++u) {
    float wv = e[u] / esum;
    wv = vld[u] ? wv : 0.f;
    int kill = (!vld[u]) || th[u] || (ad[u] == 0.f);
    w[u] = kill ? 0.f : wv;
    lw += w[u];
  }
  float wsum = block_reduce(lw, 0, red);

  ushort4 o = {f2bf(w[0]), f2bf(w[1]), f2bf(w[2]), f2bf(w[3])};
  *reinterpret_cast<ushort4*>(wout + ((size_t)b << 20) + (size_t)n * 1024 + tid * 4) = o;
  if (tid == 0) denh[b * 1024 + n] = wsum + 1.0f;
}

// ---- launch ----------------------------------------------------------------
extern "C" void kernel_launch(void* const* d_in, const int* in_sizes, int n_in,
                              void* d_out, int out_size, void* d_ws, size_t ws_size,
                              hipStream_t stream) {
  const float* X = (const float*)d_in[0];
  const float* R = (const float*)d_in[1];
  const int* adj = (const int*)d_in[2];
  const int* mask = (const int*)d_in[3];
  const float* W_Q = (const float*)d_in[4];
  const float* b_Q = (const float*)d_in[5];
  const float* W_K = (const float*)d_in[6];
  const float* b_K = (const float*)d_in[7];
  const float* W_gcn = (const float*)d_in[8];
  const float* b_gcn = (const float*)d_in[9];
  const float* W_out = (const float*)d_in[10];
  const float* b_out = (const float*)d_in[11];
  float* out = (float*)d_out;

  u16* wsu = (u16*)d_ws;
  u16* A_qk = wsu;                       // [4096][512]
  u16* XT   = A_qk + (2u << 20);         // [4][256][1024]
  u16* qbf  = XT + (1u << 20);           // [4096][256]
  u16* kbf  = qbf + (1u << 20);          // [4096][256]
  u16* WQT  = kbf + (1u << 20);          // [256][512]
  u16* WKT  = WQT + (1u << 17);          // [256][256]
  u16* WgT  = WKT + (1u << 16);          // [8][256][256]
  u16* WoT  = WgT + (1u << 19);          // [256][2048]
  u16* Tb   = WoT + (1u << 19);          // [16][1024][256]
  u16* ob   = Tb + (4u << 20);           // [16][1024][256]
  u16* obT  = ob + (4u << 20);           // [16][256][1024]
  u16* finb = obT + (4u << 20);          // [4][1024][2048]
  u16* wght = finb + (8u << 20);         // [16][1024][1024]
  float* den = (float*)(wght + (16u << 20));  // [16][1024]
  float* sc = (float*)Tb;                // [4][1024][1024] f32 — aliases Tb+ob (dead then)

  // prep: bf16 conversions + K-major transposes
  concat_k<<<8192, 256, 0, stream>>>(X, R, A_qk);
  tconv_k<<<dim3(1024, 4), 256, 0, stream>>>(X, XT, 1024);
  tconv_k<<<dim3(512, 1), 256, 0, stream>>>(W_Q, WQT, 512);
  tconv_k<<<dim3(256, 1), 256, 0, stream>>>(W_K, WKT, 256);
  tconv_k<<<dim3(256, 8), 256, 0, stream>>>(W_gcn, WgT, 256);
  tconv_k<<<dim3(2048, 1), 256, 0, stream>>>(W_out, WoT, 2048);

  // projections
  proj_k<<<dim3(4, 64), 256, 0, stream>>>(A_qk, WQT, b_Q, qbf, 512, 512, 512, 256);
  proj_k<<<dim3(4, 64), 256, 0, stream>>>(A_qk, WKT, b_K, kbf, 256, 512, 256, 256);

  // scores + z-score chain (per head; sc aliases Tb/ob which are dead here)
  for (int h = 0; h < 4; ++h) {
    mscore_k<<<dim3(16, 16, 4), 256, 0, stream>>>(qbf, kbf, sc, h);
    zscore_k<<<dim3(1024, 4), 256, 0, stream>>>(
        sc, adj, mask, wght + ((size_t)h << 22), den + h * 4096);
  }

  // GCN layer 0
  max_k<<<dim3(4, 16, 16), 256, 0, stream>>>(wght, XT, A_qk, 3, 512, 524288LL, Tb);
  mxw_k<<<dim3(4, 16, 16), 256, 0, stream>>>(Tb, WgT, b_gcn, den, ob, finb);
  // GCN layer 1
  tbf_k<<<dim3(1024, 16), 256, 0, stream>>>(ob, obT, 1024);
  max_k<<<dim3(4, 16, 16), 256, 0, stream>>>(wght, obT, ob, 15, 256, 262144LL, Tb);
  mxw_k<<<dim3(4, 16, 16), 256, 0, stream>>>(Tb, WgT + 65536, b_gcn + 256, den,
                                             nullptr, finb + 256);

  // final projection + residual
  mfinal_k<<<dim3(4, 64), 256, 0, stream>>>(finb, WoT, b_out, X, out);
}

// Round 4
// 325.309 us; speedup vs baseline: 3.3721x; 1.1669x over previous
//
#include <hip/hip_runtime.h>
#include <math.h>

typedef unsigned short u16;
typedef __attribute__((ext_vector_type(8))) short short8;
typedef __attribute__((ext_vector_type(4))) float floatx4;

#define LDS_P 72  // LDS row stride (elems); +8 pad keeps ds_read_b128 2-way max

__device__ __forceinline__ float bf2f(u16 u) {
  union { unsigned int i; float f; } v; v.i = ((unsigned int)u) << 16; return v.f;
}
__device__ __forceinline__ u16 f2bf(float f) {
  union { float f; unsigned int i; } v; v.f = f;
  unsigned int x = v.i;
  return (u16)((x + 0x7FFFu + ((x >> 16) & 1u)) >> 16);
}

// ---- stage a 64x64 bf16 tile (row-major, ldg elems) into LDS [64][LDS_P] ----
__device__ __forceinline__ void stage64(const u16* __restrict__ G, int ldg,
                                        u16* __restrict__ S, int tid) {
#pragma unroll
  for (int j = 0; j < 2; ++j) {
    int id = tid + (j << 8);
    int row = id >> 3, c8 = (id & 7) << 3;
    *reinterpret_cast<float4*>(S + row * LDS_P + c8) =
        *reinterpret_cast<const float4*>(G + (long long)row * ldg + c8);
  }
}

// ---- core: 64x64 block tile, 4 waves each 32x32 (2x2 MFMA 16x16x32) --------
__device__ __forceinline__ void mfma_loop(const u16* __restrict__ A, int lda,
                                          const u16* __restrict__ Bt, int ldb,
                                          int K, u16* As, u16* Bs,
                                          floatx4 acc[2][2], int tid) {
  int lane = tid & 63;
  int wm = ((tid >> 6) & 1) << 5, wn = ((tid >> 6) >> 1) << 5;
  int lr = lane & 15, lq8 = (lane >> 4) << 3;
  for (int k0 = 0; k0 < K; k0 += 64) {
    stage64(A + k0, lda, As, tid);
    stage64(Bt + k0, ldb, Bs, tid);
    __syncthreads();
#pragma unroll
    for (int kc = 0; kc < 64; kc += 32) {
      short8 a0 = *reinterpret_cast<const short8*>(As + (wm + lr) * LDS_P + kc + lq8);
      short8 a1 = *reinterpret_cast<const short8*>(As + (wm + 16 + lr) * LDS_P + kc + lq8);
      short8 b0 = *reinterpret_cast<const short8*>(Bs + (wn + lr) * LDS_P + kc + lq8);
      short8 b1 = *reinterpret_cast<const short8*>(Bs + (wn + 16 + lr) * LDS_P + kc + lq8);
      acc[0][0] = __builtin_amdgcn_mfma_f32_16x16x32_bf16(a0, b0, acc[0][0], 0, 0, 0);
      acc[0][1] = __builtin_amdgcn_mfma_f32_16x16x32_bf16(a0, b1, acc[0][1], 0, 0, 0);
      acc[1][0] = __builtin_amdgcn_mfma_f32_16x16x32_bf16(a1, b0, acc[1][0], 0, 0, 0);
      acc[1][1] = __builtin_amdgcn_mfma_f32_16x16x32_bf16(a1, b1, acc[1][1], 0, 0, 0);
    }
    __syncthreads();
  }
}

#define EPI_SETUP                                                     \
  int lane = threadIdx.x & 63;                                        \
  int wm = ((threadIdx.x >> 6) & 1) << 5,                             \
      wn = ((threadIdx.x >> 6) >> 1) << 5;                            \
  int lr = lane & 15, lq4 = (lane >> 4) << 2;

// ---- q/k projection: C(bf16) = A(bf16) @ Bt^T + bias ----------------------
__global__ __launch_bounds__(256) void proj_k(
    const u16* __restrict__ A, const u16* __restrict__ Bt,
    const float* __restrict__ bias, u16* __restrict__ C,
    int K, int lda, int ldb, int ldc) {
  __shared__ u16 As[64 * LDS_P], Bs[64 * LDS_P];
  int m0 = blockIdx.y << 6, n0 = blockIdx.x << 6;
  floatx4 acc[2][2] = {};
  mfma_loop(A + (long long)m0 * lda, lda, Bt + (long long)n0 * ldb, ldb, K, As, Bs,
            acc, threadIdx.x);
  EPI_SETUP
#pragma unroll
  for (int ti = 0; ti < 2; ++ti)
#pragma unroll
    for (int tj = 0; tj < 2; ++tj)
#pragma unroll
      for (int r = 0; r < 4; ++r) {
        int row = m0 + wm + ti * 16 + lq4 + r;
        int col = n0 + wn + tj * 16 + lr;
        C[(long long)row * ldc + col] = f2bf(acc[ti][tj][r] + bias[col]);
      }
}

// ---- scores (batched, 8 z-slices = 2 heads x 4 batches) --------------------
__global__ __launch_bounds__(256) void mscore_k(
    const u16* __restrict__ q, const u16* __restrict__ kb,
    float* __restrict__ sc, int h0) {
  __shared__ u16 As[64 * LDS_P], Bs[64 * LDS_P];
  int z = blockIdx.z;
  int b = z & 3, h = h0 + (z >> 2);
  int m0 = blockIdx.y << 6, n0 = blockIdx.x << 6;
  const u16* Ab = q + b * 262144 + h * 64;
  const u16* Bb = kb + b * 262144 + h * 64;
  floatx4 acc[2][2] = {};
  mfma_loop(Ab + (long long)m0 * 256, 256, Bb + (long long)n0 * 256, 256, 64, As, Bs,
            acc, threadIdx.x);
  float* Cb = sc + ((long long)z << 20);
  EPI_SETUP
#pragma unroll
  for (int ti = 0; ti < 2; ++ti)
#pragma unroll
    for (int tj = 0; tj < 2; ++tj)
#pragma unroll
      for (int r = 0; r < 4; ++r) {
        int row = m0 + wm + ti * 16 + lq4 + r;
        int col = n0 + wn + tj * 16 + lr;
        Cb[(long long)row * 1024 + col] = acc[ti][tj][r];
      }
}

// ---- T(bf16) = wght(bf16) @ srcT^T + src  (z = h*4+b) ----------------------
__global__ __launch_bounds__(256) void max_k(
    const u16* __restrict__ wght, const u16* __restrict__ srcT,
    const u16* __restrict__ addsrc, int zmask, int ldadd, long long sAdd,
    u16* __restrict__ T) {
  __shared__ u16 As[64 * LDS_P], Bs[64 * LDS_P];
  int z = blockIdx.z;
  int m0 = blockIdx.y << 6, n0 = blockIdx.x << 6;
  const u16* Ab = wght + ((long long)z << 20);
  const u16* Bb = srcT + (long long)(z & zmask) * 262144;
  const u16* addb = addsrc + (long long)(z & zmask) * sAdd;
  floatx4 acc[2][2] = {};
  mfma_loop(Ab + (long long)m0 * 1024, 1024, Bb + (long long)n0 * 1024, 1024, 1024,
            As, Bs, acc, threadIdx.x);
  u16* Tb = T + ((long long)z << 18);
  EPI_SETUP
#pragma unroll
  for (int ti = 0; ti < 2; ++ti)
#pragma unroll
    for (int tj = 0; tj < 2; ++tj)
#pragma unroll
      for (int r = 0; r < 4; ++r) {
        int row = m0 + wm + ti * 16 + lq4 + r;
        int col = n0 + wn + tj * 16 + lr;
        float v = acc[ti][tj][r] + bf2f(addb[(long long)row * ldadd + col]);
        Tb[(long long)row * 256 + col] = f2bf(v);
      }
}

// ---- layer GEMM: relu((T @ Wg^T + 2b)/den) -> fin slice (+ob) --------------
__global__ __launch_bounds__(256) void mxw_k(
    const u16* __restrict__ T, const u16* __restrict__ WgT,
    const float* __restrict__ bg, const float* __restrict__ den,
    u16* __restrict__ ob, u16* __restrict__ fin) {
  __shared__ u16 As[64 * LDS_P], Bs[64 * LDS_P];
  int z = blockIdx.z;
  int m0 = blockIdx.y << 6, n0 = blockIdx.x << 6;
  const u16* Ab = T + ((long long)z << 18);
  const u16* Bb = WgT + (long long)(z >> 2) * 131072;
  const float* bb = bg + (z >> 2) * 512;
  const float* dn = den + z * 1024;
  floatx4 acc[2][2] = {};
  mfma_loop(Ab + (long long)m0 * 256, 256, Bb + (long long)n0 * 256, 256, 256,
            As, Bs, acc, threadIdx.x);
  EPI_SETUP
#pragma unroll
  for (int ti = 0; ti < 2; ++ti)
#pragma unroll
    for (int tj = 0; tj < 2; ++tj)
#pragma unroll
      for (int r = 0; r < 4; ++r) {
        int row = m0 + wm + ti * 16 + lq4 + r;
        int col = n0 + wn + tj * 16 + lr;
        float v = (acc[ti][tj][r] + 2.f * bb[col]) / dn[row];
        v = fmaxf(v, 0.f);
        u16 bv = f2bf(v);
        fin[(long long)(z & 3) * 2097152 + (long long)row * 2048 + (z >> 2) * 512 + col] = bv;
        if (ob) ob[((long long)z << 18) + (long long)row * 256 + col] = bv;
      }
}

// ---- init: out = X + b_out -------------------------------------------------
__global__ __launch_bounds__(256) void initout_k(const float* __restrict__ X,
                                                 const float* __restrict__ bias,
                                                 float* __restrict__ out) {
  int gid = blockIdx.x * 256 + threadIdx.x;
  int col = (gid << 2) & 255;
  float4 x = reinterpret_cast<const float4*>(X)[gid];
  float4 b = *reinterpret_cast<const float4*>(bias + col);
  x.x += b.x; x.y += b.y; x.z += b.z; x.w += b.w;
  reinterpret_cast<float4*>(out)[gid] = x;
}

// ---- final split-K: out += fin @ Wo^T (atomic f32) -------------------------
__global__ __launch_bounds__(256) void mfinal_k(
    const u16* __restrict__ fin, const u16* __restrict__ WoT,
    float* __restrict__ out) {
  __shared__ u16 As[64 * LDS_P], Bs[64 * LDS_P];
  int m0 = blockIdx.y << 6, n0 = blockIdx.x << 6;
  int ks = blockIdx.z << 9;  // 4 splits of 512
  floatx4 acc[2][2] = {};
  mfma_loop(fin + (long long)m0 * 2048 + ks, 2048, WoT + (long long)n0 * 2048 + ks,
            2048, 512, As, Bs, acc, threadIdx.x);
  EPI_SETUP
#pragma unroll
  for (int ti = 0; ti < 2; ++ti)
#pragma unroll
    for (int tj = 0; tj < 2; ++tj)
#pragma unroll
      for (int r = 0; r < 4; ++r) {
        int row = m0 + wm + ti * 16 + lq4 + r;
        int col = n0 + wn + tj * 16 + lr;
        atomicAdd(out + (long long)row * 256 + col, acc[ti][tj][r]);
      }
}

// ---- prep: [X|R]->bf16 concat + X^T ---------------------------------------
__global__ __launch_bounds__(256) void xprep_k(const float* __restrict__ X,
                                               const float* __restrict__ R,
                                               u16* __restrict__ A,
                                               u16* __restrict__ XT) {
  int gid = blockIdx.x * 256 + threadIdx.x;
  if (gid < 2097152) {
    int col = gid & 511, row = gid >> 9;
    float v = (col < 256) ? X[row * 256 + col] : R[row * 256 + col - 256];
    A[gid] = f2bf(v);
  } else {
    int t = gid - 2097152;
    int b = t >> 18, r2 = t & 262143;
    int i = r2 >> 8, j = r2 & 255;
    XT[b * 262144 + j * 1024 + i] = f2bf(X[t]);
  }
}

// ---- prep: all weight transposes -> bf16 K-major ---------------------------
__global__ __launch_bounds__(256) void wprep_k(
    const float* __restrict__ W_Q, const float* __restrict__ W_K,
    const float* __restrict__ W_gcn, const float* __restrict__ W_out,
    u16* __restrict__ WQT, u16* __restrict__ WKT,
    u16* __restrict__ WgT, u16* __restrict__ WoT) {
  int gid = blockIdx.x * 256 + threadIdx.x;
  if (gid < 131072) {
    int i = gid >> 8, j = gid & 255;
    WQT[j * 512 + i] = f2bf(W_Q[gid]);
  } else if (gid < 196608) {
    int t = gid - 131072;
    int i = t >> 8, j = t & 255;
    WKT[j * 256 + i] = f2bf(W_K[t]);
  } else if (gid < 720896) {
    int t = gid - 196608;
    int z = t >> 16, r2 = t & 65535;
    int i = r2 >> 8, j = r2 & 255;
    WgT[z * 65536 + j * 256 + i] = f2bf(W_gcn[t]);
  } else if (gid < 1245184) {
    int t = gid - 720896;
    int i = t >> 8, j = t & 255;
    WoT[j * 2048 + i] = f2bf(W_out[t]);
  }
}

// ---- prep: transpose bf16 [Z][I][256] -> bf16 [Z][256][I] ------------------
__global__ __launch_bounds__(256) void tbf_k(const u16* __restrict__ src,
                                             u16* __restrict__ dst, int I) {
  int z = blockIdx.y;
  int idx = (blockIdx.x << 8) + threadIdx.x;
  int i = idx >> 8, j = idx & 255;
  long long base = (long long)z * I * 256;
  dst[base + (long long)j * I + i] = src[base + idx];
}

// ---- z-score attention, 2 heads per block -> bf16 weights ------------------
__device__ __forceinline__ float block_reduce(float v, int is_max, float* red) {
#pragma unroll
  for (int o = 32; o > 0; o >>= 1) {
    float t = __shfl_down(v, o, 64);
    v = is_max ? fmaxf(v, t) : (v + t);
  }
  int lane = threadIdx.x & 63, w = threadIdx.x >> 6;
  __syncthreads();
  if (lane == 0) red[w] = v;
  __syncthreads();
  return is_max ? fmaxf(fmaxf(red[0], red[1]), fmaxf(red[2], red[3]))
                : (red[0] + red[1] + red[2] + red[3]);
}

__global__ __launch_bounds__(256) void zscore2_k(
    const float* __restrict__ sc, const int* __restrict__ adj,
    const int* __restrict__ mask, u16* __restrict__ wout,
    float* __restrict__ denh, int h0) {
  int n = blockIdx.x, b = blockIdx.y;
  const int* arow = adj + ((long long)(b * 1024 + n)) * 1024;
  const int* mrow = mask + b * 1024;
  int tid = threadIdx.x;

  int4 a4 = *reinterpret_cast<const int4*>(arow + tid * 4);
  int4 m4 = *reinterpret_cast<const int4*>(mrow + tid * 4);
  float ad[4] = {(float)a4.x, (float)a4.y, (float)a4.z, (float)a4.w};
  int vld[4] = {m4.x == 0, m4.y == 0, m4.z == 0, m4.w == 0};

  __shared__ float red[4];

  float lc = 0.f;
#pragma unroll
  for (int u = 0; u < 4; ++u)
    if (vld[u]) lc += 1.f;
  float cnt = block_reduce(lc, 0, red);

  for (int hh = 0; hh < 2; ++hh) {
    const float* row = sc + (((long long)(hh * 4 + b)) << 20) + (long long)n * 1024;
    float4 s4 = *reinterpret_cast<const float4*>(row + tid * 4);
    float s[4] = {s4.x, s4.y, s4.z, s4.w};

    float ls = 0.f;
#pragma unroll
    for (int u = 0; u < 4; ++u)
      if (vld[u]) ls += s[u];
    float sum = block_reduce(ls, 0, red);
    float mean = sum / (cnt + 0.0001f);

    float lq = 0.f;
#pragma unroll
    for (int u = 0; u < 4; ++u)
      if (vld[u]) { float d = s[u] - mean; lq += d * d; }
    float sq = block_reduce(lq, 0, red);
    float stdv = sqrtf(sq / (cnt + 0.0001f) + 1e-10f);

    float s2[4];
    int th[4];
#pragma unroll
    for (int u = 0; u < 4; ++u) {
      float z = (s[u] - mean) / (stdv + 0.0001f);
      float zm = vld[u] ? z : 0.f;
      th[u] = (zm < 0.f);
      s2[u] = vld[u] ? (th[u] ? -1000000000.0f : zm) : -1000000000.0f;
    }
    float lm = fmaxf(fmaxf(s2[0], s2[1]), fmaxf(s2[2], s2[3]));
    float rowmax = block_reduce(lm, 1, red);

    float e[4];
    float le = 0.f;
#pragma unroll
    for (int u = 0; u < 4; ++u) {
      e[u] = (vld[u] ? expf(s2[u] - rowmax) * ad[u] : 0.f) + 1e-10f;
      le += e[u];
    }
    float esum = block_reduce(le, 0, red);

    float w[4];
    float lw = 0.f;
#pragma unroll
    for (int u = 0; u < 4; ++u) {
      float wv = e[u] / esum;
      wv = vld[u] ? wv : 0.f;
      int kill = (!vld[u]) || th[u] || (ad[u] == 0.f);
      w[u] = kill ? 0.f : wv;
      lw += w[u];
    }
    float wsum = block_reduce(lw, 0, red);

    int idx = (h0 + hh) * 4 + b;
    ushort4 o = {f2bf(w[0]), f2bf(w[1]), f2bf(w[2]), f2bf(w[3])};
    *reinterpret_cast<ushort4*>(wout + ((size_t)idx << 20) + (size_t)n * 1024 + tid * 4) = o;
    if (tid == 0) denh[idx * 1024 + n] = wsum + 1.0f;
  }
}

// ---- launch ----------------------------------------------------------------
extern "C" void kernel_launch(void* const* d_in, const int* in_sizes, int n_in,
                              void* d_out, int out_size, void* d_ws, size_t ws_size,
                              hipStream_t stream) {
  const float* X = (const float*)d_in[0];
  const float* R = (const float*)d_in[1];
  const int* adj = (const int*)d_in[2];
  const int* mask = (const int*)d_in[3];
  const float* W_Q = (const float*)d_in[4];
  const float* b_Q = (const float*)d_in[5];
  const float* W_K = (const float*)d_in[6];
  const float* b_K = (const float*)d_in[7];
  const float* W_gcn = (const float*)d_in[8];
  const float* b_gcn = (const float*)d_in[9];
  const float* W_out = (const float*)d_in[10];
  const float* b_out = (const float*)d_in[11];
  float* out = (float*)d_out;

  u16* wsu = (u16*)d_ws;
  u16* A_qk = wsu;                       // [4096][512]
  u16* XT   = A_qk + (2u << 20);         // [4][256][1024]
  u16* qbf  = XT + (1u << 20);           // [4096][256]
  u16* kbf  = qbf + (1u << 20);          // [4096][256]
  u16* WQT  = kbf + (1u << 20);          // [256][512]
  u16* WKT  = WQT + (1u << 17);          // [256][256]
  u16* WgT  = WKT + (1u << 16);          // [8][256][256]
  u16* WoT  = WgT + (1u << 19);          // [256][2048]
  u16* Tb   = WoT + (1u << 19);          // [16][1024][256]
  u16* ob   = Tb + (4u << 20);           // [16][1024][256]
  u16* obT  = ob + (4u << 20);           // [16][256][1024]
  u16* finb = obT + (4u << 20);          // [4][1024][2048]
  u16* wght = finb + (8u << 20);         // [16][1024][1024]
  float* den = (float*)(wght + (16u << 20));  // [16][1024]
  float* sc = (float*)Tb;  // [8][1024][1024] f32 overlay (Tb..fin dead then)

  // prep
  xprep_k<<<12288, 256, 0, stream>>>(X, R, A_qk, XT);
  wprep_k<<<4864, 256, 0, stream>>>(W_Q, W_K, W_gcn, W_out, WQT, WKT, WgT, WoT);
  initout_k<<<1024, 256, 0, stream>>>(X, b_out, out);

  // projections
  proj_k<<<dim3(4, 64), 256, 0, stream>>>(A_qk, WQT, b_Q, qbf, 512, 512, 512, 256);
  proj_k<<<dim3(4, 64), 256, 0, stream>>>(A_qk, WKT, b_K, kbf, 256, 512, 256, 256);

  // scores + z-score, 2 heads at a time (sc overlays dead Tb..fin region)
  for (int h0 = 0; h0 < 4; h0 += 2) {
    mscore_k<<<dim3(16, 16, 8), 256, 0, stream>>>(qbf, kbf, sc, h0);
    zscore2_k<<<dim3(1024, 4), 256, 0, stream>>>(sc, adj, mask, wght, den, h0);
  }

  // GCN layer 0
  max_k<<<dim3(4, 16, 16), 256, 0, stream>>>(wght, XT, A_qk, 3, 512, 524288LL, Tb);
  mxw_k<<<dim3(4, 16, 16), 256, 0, stream>>>(Tb, WgT, b_gcn, den, ob, finb);
  // GCN layer 1
  tbf_k<<<dim3(1024, 16), 256, 0, stream>>>(ob, obT, 1024);
  max_k<<<dim3(4, 16, 16), 256, 0, stream>>>(wght, obT, ob, 15, 256, 262144LL, Tb);
  mxw_k<<<dim3(4, 16, 16), 256, 0, stream>>>(Tb, WgT + 65536, b_gcn + 256, den,
                                             nullptr, finb + 256);

  // final split-K accumulate
  mfinal_k<<<dim3(4, 64, 4), 256, 0, stream>>>(finb, WoT, out);
}

// Round 5
// 292.073 us; speedup vs baseline: 3.7558x; 1.1138x over previous
//
#include <hip/hip_runtime.h>
#include <math.h>

typedef unsigned short u16;
typedef __attribute__((ext_vector_type(8))) short short8;
typedef __attribute__((ext_vector_type(4))) float floatx4;

#define LDS_P 72  // padded LDS row stride for 64-wide tiles

__device__ __forceinline__ float bf2f(u16 u) {
  union { unsigned int i; float f; } v; v.i = ((unsigned int)u) << 16; return v.f;
}
__device__ __forceinline__ u16 f2bf(float f) {
  union { float f; unsigned int i; } v; v.f = f;
  unsigned int x = v.i;
  return (u16)((x + 0x7FFFu + ((x >> 16) & 1u)) >> 16);
}

// ---- stage a 64x64 bf16 tile (row-major, ldg elems) into LDS [64][LDS_P] ----
__device__ __forceinline__ void stage64(const u16* __restrict__ G, int ldg,
                                        u16* __restrict__ S, int tid) {
#pragma unroll
  for (int j = 0; j < 2; ++j) {
    int id = tid + (j << 8);
    int row = id >> 3, c8 = (id & 7) << 3;
    *reinterpret_cast<float4*>(S + row * LDS_P + c8) =
        *reinterpret_cast<const float4*>(G + (long long)row * ldg + c8);
  }
}

// ---- core: 64x64 block tile, 4 waves each 32x32 (2x2 MFMA 16x16x32) --------
__device__ __forceinline__ void mfma_loop(const u16* __restrict__ A, int lda,
                                          const u16* __restrict__ Bt, int ldb,
                                          int K, u16* As, u16* Bs,
                                          floatx4 acc[2][2], int tid) {
  int lane = tid & 63;
  int wm = ((tid >> 6) & 1) << 5, wn = ((tid >> 6) >> 1) << 5;
  int lr = lane & 15, lq8 = (lane >> 4) << 3;
  for (int k0 = 0; k0 < K; k0 += 64) {
    stage64(A + k0, lda, As, tid);
    stage64(Bt + k0, ldb, Bs, tid);
    __syncthreads();
#pragma unroll
    for (int kc = 0; kc < 64; kc += 32) {
      short8 a0 = *reinterpret_cast<const short8*>(As + (wm + lr) * LDS_P + kc + lq8);
      short8 a1 = *reinterpret_cast<const short8*>(As + (wm + 16 + lr) * LDS_P + kc + lq8);
      short8 b0 = *reinterpret_cast<const short8*>(Bs + (wn + lr) * LDS_P + kc + lq8);
      short8 b1 = *reinterpret_cast<const short8*>(Bs + (wn + 16 + lr) * LDS_P + kc + lq8);
      acc[0][0] = __builtin_amdgcn_mfma_f32_16x16x32_bf16(a0, b0, acc[0][0], 0, 0, 0);
      acc[0][1] = __builtin_amdgcn_mfma_f32_16x16x32_bf16(a0, b1, acc[0][1], 0, 0, 0);
      acc[1][0] = __builtin_amdgcn_mfma_f32_16x16x32_bf16(a1, b0, acc[1][0], 0, 0, 0);
      acc[1][1] = __builtin_amdgcn_mfma_f32_16x16x32_bf16(a1, b1, acc[1][1], 0, 0, 0);
    }
    __syncthreads();
  }
}

#define EPI_SETUP                                                     \
  int lane = threadIdx.x & 63;                                        \
  int wm = ((threadIdx.x >> 6) & 1) << 5,                             \
      wn = ((threadIdx.x >> 6) >> 1) << 5;                            \
  int lr = lane & 15, lq4 = (lane >> 4) << 2;

// ---- q+k projections in one launch (z=0:Q, z=1:K) --------------------------
__global__ __launch_bounds__(256) void proj2_k(
    const u16* __restrict__ A, const u16* __restrict__ WQT,
    const u16* __restrict__ WKT, const float* __restrict__ b_Q,
    const float* __restrict__ b_K, u16* __restrict__ qbf,
    u16* __restrict__ kbf) {
  __shared__ u16 As[64 * LDS_P], Bs[64 * LDS_P];
  int z = blockIdx.z;
  int m0 = blockIdx.y << 6, n0 = blockIdx.x << 6;
  int K = z ? 256 : 512, ldb = z ? 256 : 512;
  const u16* Bt = z ? WKT : WQT;
  const float* bias = z ? b_K : b_Q;
  u16* C = z ? kbf : qbf;
  floatx4 acc[2][2] = {};
  mfma_loop(A + (long long)m0 * 512, 512, Bt + (long long)n0 * ldb, ldb, K, As, Bs,
            acc, threadIdx.x);
  EPI_SETUP
#pragma unroll
  for (int ti = 0; ti < 2; ++ti)
#pragma unroll
    for (int tj = 0; tj < 2; ++tj)
#pragma unroll
      for (int r = 0; r < 4; ++r) {
        int row = m0 + wm + ti * 16 + lq4 + r;
        int col = n0 + wn + tj * 16 + lr;
        C[(long long)row * 256 + col] = f2bf(acc[ti][tj][r] + bias[col]);
      }
}

// ---- scores, all 16 z-slices (z = h*4+b) -----------------------------------
__global__ __launch_bounds__(256) void mscore_k(
    const u16* __restrict__ q, const u16* __restrict__ kb,
    float* __restrict__ sc) {
  __shared__ u16 As[64 * LDS_P], Bs[64 * LDS_P];
  int z = blockIdx.z;
  int b = z & 3, h = z >> 2;
  int m0 = blockIdx.y << 6, n0 = blockIdx.x << 6;
  const u16* Ab = q + b * 262144 + h * 64;
  const u16* Bb = kb + b * 262144 + h * 64;
  floatx4 acc[2][2] = {};
  mfma_loop(Ab + (long long)m0 * 256, 256, Bb + (long long)n0 * 256, 256, 64, As, Bs,
            acc, threadIdx.x);
  float* Cb = sc + ((long long)z << 20);
  EPI_SETUP
#pragma unroll
  for (int ti = 0; ti < 2; ++ti)
#pragma unroll
    for (int tj = 0; tj < 2; ++tj)
#pragma unroll
      for (int r = 0; r < 4; ++r) {
        int row = m0 + wm + ti * 16 + lq4 + r;
        int col = n0 + wn + tj * 16 + lr;
        Cb[(long long)row * 1024 + col] = acc[ti][tj][r];
      }
}

// ---- fused GCN layer: T = wght@srcT^T + src (regs) -> LDS -> out GEMM ------
__global__ __launch_bounds__(256) void gcn_k(
    const u16* __restrict__ wght, const u16* __restrict__ srcT,
    const u16* __restrict__ addsrc, int zmask, int ldadd, long long sAdd,
    const u16* __restrict__ WgT_all, const float* __restrict__ bg_all,
    const float* __restrict__ den, int l,
    u16* __restrict__ ob, u16* __restrict__ fin) {
  __shared__ u16 lds[35328];
  u16* As = lds;             // [64][72]  stage 1
  u16* Bs = lds + 4608;      // [256][72] stage 1
  u16* Ts = lds;             // [64][264] stage 2 (overwrites stage-1 area)
  u16* Ws = lds + 16896;     // [256][72] stage 2
  int tid = threadIdx.x;
  int m0 = blockIdx.x << 6;
  int z = blockIdx.y;
  int lane = tid & 63, w = tid >> 6;
  int lr = lane & 15, lq8 = (lane >> 4) << 3, lq4 = (lane >> 4) << 2;

  const u16* Aw = wght + ((long long)z << 20) + (long long)m0 * 1024;
  const u16* Bt = srcT + (long long)(z & zmask) * 262144;
  const u16* addb = addsrc + (long long)(z & zmask) * sAdd;
  int idx2 = (z >> 2) * 2 + l;
  const u16* Wg = WgT_all + (long long)idx2 * 65536;

  floatx4 acc[4][4] = {};
  // ---- stage 1: T tile 64x256, K=1024 ----
  for (int k0 = 0; k0 < 1024; k0 += 64) {
#pragma unroll
    for (int j = 0; j < 2; ++j) {
      int id = tid + (j << 8);
      int row = id >> 3, c8 = (id & 7) << 3;
      *reinterpret_cast<float4*>(As + row * 72 + c8) =
          *reinterpret_cast<const float4*>(Aw + (long long)row * 1024 + k0 + c8);
    }
#pragma unroll
    for (int j = 0; j < 8; ++j) {
      int id = tid + (j << 8);
      int row = id >> 3, c8 = (id & 7) << 3;
      *reinterpret_cast<float4*>(Bs + row * 72 + c8) =
          *reinterpret_cast<const float4*>(Bt + (long long)row * 1024 + k0 + c8);
    }
    __syncthreads();
#pragma unroll
    for (int kc = 0; kc < 64; kc += 32) {
      short8 a[4], b[4];
#pragma unroll
      for (int t = 0; t < 4; ++t) {
        a[t] = *reinterpret_cast<const short8*>(As + (t * 16 + lr) * 72 + kc + lq8);
        b[t] = *reinterpret_cast<const short8*>(Bs + ((w << 6) + t * 16 + lr) * 72 + kc + lq8);
      }
#pragma unroll
      for (int ti = 0; ti < 4; ++ti)
#pragma unroll
        for (int tj = 0; tj < 4; ++tj)
          acc[ti][tj] =
              __builtin_amdgcn_mfma_f32_16x16x32_bf16(a[ti], b[tj], acc[ti][tj], 0, 0, 0);
    }
    __syncthreads();
  }
  // ---- T (+src) -> LDS in A-operand layout; zero accs ----
#pragma unroll
  for (int ti = 0; ti < 4; ++ti)
#pragma unroll
    for (int tj = 0; tj < 4; ++tj)
#pragma unroll
      for (int r = 0; r < 4; ++r) {
        int row = ti * 16 + lq4 + r;
        int col = (w << 6) + tj * 16 + lr;
        float v = acc[ti][tj][r] + bf2f(addb[(long long)(m0 + row) * ldadd + col]);
        Ts[row * 264 + col] = f2bf(v);
        acc[ti][tj][r] = 0.f;
      }
  __syncthreads();
  // ---- stage 2: out = T @ Wg^T, K=256 ----
  for (int kc0 = 0; kc0 < 256; kc0 += 64) {
#pragma unroll
    for (int j = 0; j < 8; ++j) {
      int id = tid + (j << 8);
      int row = id >> 3, c8 = (id & 7) << 3;
      *reinterpret_cast<float4*>(Ws + row * 72 + c8) =
          *reinterpret_cast<const float4*>(Wg + (long long)row * 256 + kc0 + c8);
    }
    __syncthreads();
#pragma unroll
    for (int kc = 0; kc < 64; kc += 32) {
      short8 a[4], b[4];
#pragma unroll
      for (int t = 0; t < 4; ++t) {
        a[t] = *reinterpret_cast<const short8*>(Ts + (t * 16 + lr) * 264 + kc0 + kc + lq8);
        b[t] = *reinterpret_cast<const short8*>(Ws + ((w << 6) + t * 16 + lr) * 72 + kc + lq8);
      }
#pragma unroll
      for (int ti = 0; ti < 4; ++ti)
#pragma unroll
        for (int tj = 0; tj < 4; ++tj)
          acc[ti][tj] =
              __builtin_amdgcn_mfma_f32_16x16x32_bf16(a[ti], b[tj], acc[ti][tj], 0, 0, 0);
    }
    __syncthreads();
  }
  // ---- epilogue: relu((. + 2b)/den) -> fin slice (+ob) ----
  const float* bb = bg_all + idx2 * 256;
  const float* dn = den + z * 1024;
  long long finbase = (long long)(z & 3) * 2097152 + idx2 * 256;
#pragma unroll
  for (int ti = 0; ti < 4; ++ti)
#pragma unroll
    for (int tj = 0; tj < 4; ++tj)
#pragma unroll
      for (int r = 0; r < 4; ++r) {
        int row = m0 + ti * 16 + lq4 + r;
        int col = (w << 6) + tj * 16 + lr;
        float v = (acc[ti][tj][r] + 2.f * bb[col]) / dn[row];
        v = fmaxf(v, 0.f);
        u16 bv = f2bf(v);
        fin[finbase + (long long)row * 2048 + col] = bv;
        if (ob) ob[((long long)z << 18) + (long long)row * 256 + col] = bv;
      }
}

// ---- init: out = X + b_out -------------------------------------------------
__global__ __launch_bounds__(256) void initout_k(const float* __restrict__ X,
                                                 const float* __restrict__ bias,
                                                 float* __restrict__ out) {
  int gid = blockIdx.x * 256 + threadIdx.x;
  int col = (gid << 2) & 255;
  float4 x = reinterpret_cast<const float4*>(X)[gid];
  float4 b = *reinterpret_cast<const float4*>(bias + col);
  x.x += b.x; x.y += b.y; x.z += b.z; x.w += b.w;
  reinterpret_cast<float4*>(out)[gid] = x;
}

// ---- final split-K: out += fin @ Wo^T (atomic f32) -------------------------
__global__ __launch_bounds__(256) void mfinal_k(
    const u16* __restrict__ fin, const u16* __restrict__ WoT,
    float* __restrict__ out) {
  __shared__ u16 As[64 * LDS_P], Bs[64 * LDS_P];
  int m0 = blockIdx.y << 6, n0 = blockIdx.x << 6;
  int ks = blockIdx.z << 9;  // 4 splits of 512
  floatx4 acc[2][2] = {};
  mfma_loop(fin + (long long)m0 * 2048 + ks, 2048, WoT + (long long)n0 * 2048 + ks,
            2048, 512, As, Bs, acc, threadIdx.x);
  EPI_SETUP
#pragma unroll
  for (int ti = 0; ti < 2; ++ti)
#pragma unroll
    for (int tj = 0; tj < 2; ++tj)
#pragma unroll
      for (int r = 0; r < 4; ++r) {
        int row = m0 + wm + ti * 16 + lq4 + r;
        int col = n0 + wn + tj * 16 + lr;
        atomicAdd(out + (long long)row * 256 + col, acc[ti][tj][r]);
      }
}

// ---- prep: [X|R]->bf16 concat + X^T ---------------------------------------
__global__ __launch_bounds__(256) void xprep_k(const float* __restrict__ X,
                                               const float* __restrict__ R,
                                               u16* __restrict__ A,
                                               u16* __restrict__ XT) {
  int gid = blockIdx.x * 256 + threadIdx.x;
  if (gid < 2097152) {
    int col = gid & 511, row = gid >> 9;
    float v = (col < 256) ? X[row * 256 + col] : R[row * 256 + col - 256];
    A[gid] = f2bf(v);
  } else {
    int t = gid - 2097152;
    int b = t >> 18, r2 = t & 262143;
    int i = r2 >> 8, j = r2 & 255;
    XT[b * 262144 + j * 1024 + i] = f2bf(X[t]);
  }
}

// ---- prep: all weight transposes -> bf16 K-major ---------------------------
__global__ __launch_bounds__(256) void wprep_k(
    const float* __restrict__ W_Q, const float* __restrict__ W_K,
    const float* __restrict__ W_gcn, const float* __restrict__ W_out,
    u16* __restrict__ WQT, u16* __restrict__ WKT,
    u16* __restrict__ WgT, u16* __restrict__ WoT) {
  int gid = blockIdx.x * 256 + threadIdx.x;
  if (gid < 131072) {
    int i = gid >> 8, j = gid & 255;
    WQT[j * 512 + i] = f2bf(W_Q[gid]);
  } else if (gid < 196608) {
    int t = gid - 131072;
    int i = t >> 8, j = t & 255;
    WKT[j * 256 + i] = f2bf(W_K[t]);
  } else if (gid < 720896) {
    int t = gid - 196608;
    int z = t >> 16, r2 = t & 65535;
    int i = r2 >> 8, j = r2 & 255;
    WgT[z * 65536 + j * 256 + i] = f2bf(W_gcn[t]);
  } else if (gid < 1245184) {
    int t = gid - 720896;
    int i = t >> 8, j = t & 255;
    WoT[j * 2048 + i] = f2bf(W_out[t]);
  }
}

// ---- prep: transpose bf16 [Z][I][256] -> bf16 [Z][256][I] ------------------
__global__ __launch_bounds__(256) void tbf_k(const u16* __restrict__ src,
                                             u16* __restrict__ dst, int I) {
  int z = blockIdx.y;
  int idx = (blockIdx.x << 8) + threadIdx.x;
  int i = idx >> 8, j = idx & 255;
  long long base = (long long)z * I * 256;
  dst[base + (long long)j * I + i] = src[base + idx];
}

// ---- z-score attention, all 4 heads per block -> bf16 weights --------------
__device__ __forceinline__ float block_reduce(float v, int is_max, float* red) {
#pragma unroll
  for (int o = 32; o > 0; o >>= 1) {
    float t = __shfl_down(v, o, 64);
    v = is_max ? fmaxf(v, t) : (v + t);
  }
  int lane = threadIdx.x & 63, w = threadIdx.x >> 6;
  __syncthreads();
  if (lane == 0) red[w] = v;
  __syncthreads();
  return is_max ? fmaxf(fmaxf(red[0], red[1]), fmaxf(red[2], red[3]))
                : (red[0] + red[1] + red[2] + red[3]);
}

__global__ __launch_bounds__(256) void zscore4_k(
    const float* __restrict__ sc, const int* __restrict__ adj,
    const int* __restrict__ mask, u16* __restrict__ wout,
    float* __restrict__ denh) {
  int n = blockIdx.x, b = blockIdx.y;
  const int* arow = adj + ((long long)(b * 1024 + n)) * 1024;
  const int* mrow = mask + b * 1024;
  int tid = threadIdx.x;

  int4 a4 = *reinterpret_cast<const int4*>(arow + tid * 4);
  int4 m4 = *reinterpret_cast<const int4*>(mrow + tid * 4);
  float ad[4] = {(float)a4.x, (float)a4.y, (float)a4.z, (float)a4.w};
  int vld[4] = {m4.x == 0, m4.y == 0, m4.z == 0, m4.w == 0};

  __shared__ float red[4];

  float lc = 0.f;
#pragma unroll
  for (int u = 0; u < 4; ++u)
    if (vld[u]) lc += 1.f;
  float cnt = block_reduce(lc, 0, red);

  for (int h = 0; h < 4; ++h) {
    int z = h * 4 + b;
    const float* row = sc + ((long long)z << 20) + (long long)n * 1024;
    float4 s4 = *reinterpret_cast<const float4*>(row + tid * 4);
    float s[4] = {s4.x, s4.y, s4.z, s4.w};

    float ls = 0.f;
#pragma unroll
    for (int u = 0; u < 4; ++u)
      if (vld[u]) ls += s[u];
    float sum = block_reduce(ls, 0, red);
    float mean = sum / (cnt + 0.0001f);

    float lq = 0.f;
#pragma unroll
    for (int u = 0; u < 4; ++u)
      if (vld[u]) { float d = s[u] - mean; lq += d * d; }
    float sq = block_reduce(lq, 0, red);
    float stdv = sqrtf(sq / (cnt + 0.0001f) + 1e-10f);

    float s2[4];
    int th[4];
#pragma unroll
    for (int u = 0; u < 4; ++u) {
      float zz = (s[u] - mean) / (stdv + 0.0001f);
      float zm = vld[u] ? zz : 0.f;
      th[u] = (zm < 0.f);
      s2[u] = vld[u] ? (th[u] ? -1000000000.0f : zm) : -1000000000.0f;
    }
    float lm = fmaxf(fmaxf(s2[0], s2[1]), fmaxf(s2[2], s2[3]));
    float rowmax = block_reduce(lm, 1, red);

    float e[4];
    float le = 0.f;
#pragma unroll
    for (int u = 0; u < 4; ++u) {
      e[u] = (vld[u] ? expf(s2[u] - rowmax) * ad[u] : 0.f) + 1e-10f;
      le += e[u];
    }
    float esum = block_reduce(le, 0, red);

    float w[4];
    float lw = 0.f;
#pragma unroll
    for (int u = 0; u < 4; ++u) {
      float wv = e[u] / esum;
      wv = vld[u] ? wv : 0.f;
      int kill = (!vld[u]) || th[u] || (ad[u] == 0.f);
      w[u] = kill ? 0.f : wv;
      lw += w[u];
    }
    float wsum = block_reduce(lw, 0, red);

    ushort4 o = {f2bf(w[0]), f2bf(w[1]), f2bf(w[2]), f2bf(w[3])};
    *reinterpret_cast<ushort4*>(wout + ((size_t)z << 20) + (size_t)n * 1024 + tid * 4) = o;
    if (tid == 0) denh[z * 1024 + n] = wsum + 1.0f;
  }
}

// ---- launch ----------------------------------------------------------------
extern "C" void kernel_launch(void* const* d_in, const int* in_sizes, int n_in,
                              void* d_out, int out_size, void* d_ws, size_t ws_size,
                              hipStream_t stream) {
  const float* X = (const float*)d_in[0];
  const float* R = (const float*)d_in[1];
  const int* adj = (const int*)d_in[2];
  const int* mask = (const int*)d_in[3];
  const float* W_Q = (const float*)d_in[4];
  const float* b_Q = (const float*)d_in[5];
  const float* W_K = (const float*)d_in[6];
  const float* b_K = (const float*)d_in[7];
  const float* W_gcn = (const float*)d_in[8];
  const float* b_gcn = (const float*)d_in[9];
  const float* W_out = (const float*)d_in[10];
  const float* b_out = (const float*)d_in[11];
  float* out = (float*)d_out;

  u16* wsu = (u16*)d_ws;
  u16* A_qk = wsu;                        // [4096][512]      2M u16
  u16* qbf  = A_qk + (2u << 20);          // [4096][256]      1M
  u16* kbf  = qbf + (1u << 20);           // [4096][256]      1M
  u16* XT   = kbf + (1u << 20);           // [4][256][1024]   1M
  u16* WQT  = XT + (1u << 20);            // [256][512]       128K
  u16* WKT  = WQT + (1u << 17);           // [256][256]       64K
  u16* WgT  = WKT + (1u << 16);           // [8][256][256]    512K
  u16* WoT  = WgT + (1u << 19);           // [256][2048]      512K
  u16* ob   = WoT + (1u << 19);           // [16][1024][256]  4M
  u16* obT  = ob + (4u << 20);            // [16][256][1024]  4M
  u16* finb = obT + (4u << 20);           // [4][1024][2048]  8M
  u16* wght = finb + (8u << 20);          // [16][1024][1024] 16M
  float* den = (float*)(wght + (16u << 20));   // [16][1024]
  float* sc  = den + (1 << 14);                // [16][1024][1024] f32 (64 MB)

  // prep
  xprep_k<<<12288, 256, 0, stream>>>(X, R, A_qk, XT);
  wprep_k<<<4864, 256, 0, stream>>>(W_Q, W_K, W_gcn, W_out, WQT, WKT, WgT, WoT);
  initout_k<<<1024, 256, 0, stream>>>(X, b_out, out);

  // q & k projections (one launch)
  proj2_k<<<dim3(4, 64, 2), 256, 0, stream>>>(A_qk, WQT, WKT, b_Q, b_K, qbf, kbf);

  // scores (all 16 slices) + z-score chain (one pass, adj read once)
  mscore_k<<<dim3(16, 16, 16), 256, 0, stream>>>(qbf, kbf, sc);
  zscore4_k<<<dim3(1024, 4), 256, 0, stream>>>(sc, adj, mask, wght, den);

  // fused GCN layers
  gcn_k<<<dim3(16, 16), 256, 0, stream>>>(wght, XT, A_qk, 3, 512, 524288LL,
                                          WgT, b_gcn, den, 0, ob, finb);
  tbf_k<<<dim3(1024, 16), 256, 0, stream>>>(ob, obT, 1024);
  gcn_k<<<dim3(16, 16), 256, 0, stream>>>(wght, obT, ob, 15, 256, 262144LL,
                                          WgT, b_gcn, den, 1, nullptr, finb);

  // final split-K accumulate
  mfinal_k<<<dim3(4, 64, 4), 256, 0, stream>>>(finb, WoT, out);
}

// Round 6
// 248.032 us; speedup vs baseline: 4.4227x; 1.1776x over previous
//
#include <hip/hip_runtime.h>
#include <math.h>

typedef unsigned short u16;
typedef __attribute__((ext_vector_type(8))) short short8;
typedef __attribute__((ext_vector_type(4))) float floatx4;

#define LDS_P 72  // padded LDS row stride for 64-wide tiles

__device__ __forceinline__ float bf2f(u16 u) {
  union { unsigned int i; float f; } v; v.i = ((unsigned int)u) << 16; return v.f;
}
__device__ __forceinline__ u16 f2bf(float f) {
  union { float f; unsigned int i; } v; v.f = f;
  unsigned int x = v.i;
  return (u16)((x + 0x7FFFu + ((x >> 16) & 1u)) >> 16);
}

// ---- stage a 64x64 bf16 tile (row-major, ldg elems) into LDS [64][LDS_P] ----
__device__ __forceinline__ void stage64(const u16* __restrict__ G, int ldg,
                                        u16* __restrict__ S, int tid) {
#pragma unroll
  for (int j = 0; j < 2; ++j) {
    int id = tid + (j << 8);
    int row = id >> 3, c8 = (id & 7) << 3;
    *reinterpret_cast<float4*>(S + row * LDS_P + c8) =
        *reinterpret_cast<const float4*>(G + (long long)row * ldg + c8);
  }
}

// ---- core: 64x64 block tile, 4 waves each 32x32 (2x2 MFMA 16x16x32) --------
__device__ __forceinline__ void mfma_loop(const u16* __restrict__ A, int lda,
                                          const u16* __restrict__ Bt, int ldb,
                                          int K, u16* As, u16* Bs,
                                          floatx4 acc[2][2], int tid) {
  int lane = tid & 63;
  int wm = ((tid >> 6) & 1) << 5, wn = ((tid >> 6) >> 1) << 5;
  int lr = lane & 15, lq8 = (lane >> 4) << 3;
  for (int k0 = 0; k0 < K; k0 += 64) {
    stage64(A + k0, lda, As, tid);
    stage64(Bt + k0, ldb, Bs, tid);
    __syncthreads();
#pragma unroll
    for (int kc = 0; kc < 64; kc += 32) {
      short8 a0 = *reinterpret_cast<const short8*>(As + (wm + lr) * LDS_P + kc + lq8);
      short8 a1 = *reinterpret_cast<const short8*>(As + (wm + 16 + lr) * LDS_P + kc + lq8);
      short8 b0 = *reinterpret_cast<const short8*>(Bs + (wn + lr) * LDS_P + kc + lq8);
      short8 b1 = *reinterpret_cast<const short8*>(Bs + (wn + 16 + lr) * LDS_P + kc + lq8);
      acc[0][0] = __builtin_amdgcn_mfma_f32_16x16x32_bf16(a0, b0, acc[0][0], 0, 0, 0);
      acc[0][1] = __builtin_amdgcn_mfma_f32_16x16x32_bf16(a0, b1, acc[0][1], 0, 0, 0);
      acc[1][0] = __builtin_amdgcn_mfma_f32_16x16x32_bf16(a1, b0, acc[1][0], 0, 0, 0);
      acc[1][1] = __builtin_amdgcn_mfma_f32_16x16x32_bf16(a1, b1, acc[1][1], 0, 0, 0);
    }
    __syncthreads();
  }
}

#define EPI_SETUP                                                     \
  int lane = threadIdx.x & 63;                                        \
  int wm = ((threadIdx.x >> 6) & 1) << 5,                             \
      wn = ((threadIdx.x >> 6) >> 1) << 5;                            \
  int lr = lane & 15, lq4 = (lane >> 4) << 2;

// ---- q+k projections in one launch (z=0:Q, z=1:K) --------------------------
__global__ __launch_bounds__(256) void proj2_k(
    const u16* __restrict__ A, const u16* __restrict__ WQT,
    const u16* __restrict__ WKT, const float* __restrict__ b_Q,
    const float* __restrict__ b_K, u16* __restrict__ qbf,
    u16* __restrict__ kbf) {
  __shared__ u16 As[64 * LDS_P], Bs[64 * LDS_P];
  int z = blockIdx.z;
  int m0 = blockIdx.y << 6, n0 = blockIdx.x << 6;
  int K = z ? 256 : 512, ldb = z ? 256 : 512;
  const u16* Bt = z ? WKT : WQT;
  const float* bias = z ? b_K : b_Q;
  u16* C = z ? kbf : qbf;
  floatx4 acc[2][2] = {};
  mfma_loop(A + (long long)m0 * 512, 512, Bt + (long long)n0 * ldb, ldb, K, As, Bs,
            acc, threadIdx.x);
  EPI_SETUP
#pragma unroll
  for (int ti = 0; ti < 2; ++ti)
#pragma unroll
    for (int tj = 0; tj < 2; ++tj)
#pragma unroll
      for (int r = 0; r < 4; ++r) {
        int row = m0 + wm + ti * 16 + lq4 + r;
        int col = n0 + wn + tj * 16 + lr;
        C[(long long)row * 256 + col] = f2bf(acc[ti][tj][r] + bias[col]);
      }
}

// ---- scores, all 16 z-slices (z = h*4+b), bf16 output ----------------------
__global__ __launch_bounds__(256) void mscore_k(
    const u16* __restrict__ q, const u16* __restrict__ kb,
    u16* __restrict__ sc) {
  __shared__ u16 As[64 * LDS_P], Bs[64 * LDS_P];
  int z = blockIdx.z;
  int b = z & 3, h = z >> 2;
  int m0 = blockIdx.y << 6, n0 = blockIdx.x << 6;
  const u16* Ab = q + b * 262144 + h * 64;
  const u16* Bb = kb + b * 262144 + h * 64;
  floatx4 acc[2][2] = {};
  mfma_loop(Ab + (long long)m0 * 256, 256, Bb + (long long)n0 * 256, 256, 64, As, Bs,
            acc, threadIdx.x);
  u16* Cb = sc + ((long long)z << 20);
  EPI_SETUP
#pragma unroll
  for (int ti = 0; ti < 2; ++ti)
#pragma unroll
    for (int tj = 0; tj < 2; ++tj)
#pragma unroll
      for (int r = 0; r < 4; ++r) {
        int row = m0 + wm + ti * 16 + lq4 + r;
        int col = n0 + wn + tj * 16 + lr;
        Cb[(long long)row * 1024 + col] = f2bf(acc[ti][tj][r]);
      }
}

// ---- wave-level reductions (no barriers) -----------------------------------
__device__ __forceinline__ float wred_sum(float v) {
#pragma unroll
  for (int m = 32; m > 0; m >>= 1) v += __shfl_xor(v, m, 64);
  return v;
}
__device__ __forceinline__ void wred_sum2(float& a, float& b) {
#pragma unroll
  for (int m = 32; m > 0; m >>= 1) {
    float ta = __shfl_xor(a, m, 64);
    float tb = __shfl_xor(b, m, 64);
    a += ta; b += tb;
  }
}
__device__ __forceinline__ float wred_max(float v) {
#pragma unroll
  for (int m = 32; m > 0; m >>= 1) v = fmaxf(v, __shfl_xor(v, m, 64));
  return v;
}

// ---- z-score attention: one wave per row, all 4 heads ----------------------
__global__ __launch_bounds__(256) void zscore_w(
    const u16* __restrict__ sc, const int* __restrict__ adj,
    const int* __restrict__ mask, u16* __restrict__ wout,
    float* __restrict__ denh) {
  int wv = threadIdx.x >> 6, lane = threadIdx.x & 63;
  int row = (blockIdx.x << 2) + wv;  // 0..4095
  int b = row >> 10, n = row & 1023;
  int e0 = lane << 4;  // 16 elems per lane
  const int* arow = adj + ((long long)row << 10) + e0;
  const int* mrow = mask + (b << 10) + e0;

  unsigned int vbits = 0, abits = 0;
#pragma unroll
  for (int q = 0; q < 4; ++q) {
    int4 a4 = *reinterpret_cast<const int4*>(arow + (q << 2));
    int4 m4 = *reinterpret_cast<const int4*>(mrow + (q << 2));
    vbits |= (unsigned)(m4.x == 0) << (q * 4);
    vbits |= (unsigned)(m4.y == 0) << (q * 4 + 1);
    vbits |= (unsigned)(m4.z == 0) << (q * 4 + 2);
    vbits |= (unsigned)(m4.w == 0) << (q * 4 + 3);
    abits |= (unsigned)(a4.x != 0) << (q * 4);
    abits |= (unsigned)(a4.y != 0) << (q * 4 + 1);
    abits |= (unsigned)(a4.z != 0) << (q * 4 + 2);
    abits |= (unsigned)(a4.w != 0) << (q * 4 + 3);
  }
  float cnt = wred_sum((float)__popc(vbits));
  float cnteff = cnt + 0.0001f;

  for (int h = 0; h < 4; ++h) {
    int z = (h << 2) + b;
    const u16* srow = sc + ((long long)z << 20) + ((long long)n << 10) + e0;
    float s[16];
#pragma unroll
    for (int q = 0; q < 2; ++q) {
      uint4 u = *reinterpret_cast<const uint4*>(srow + (q << 3));
      unsigned int uu[4] = {u.x, u.y, u.z, u.w};
#pragma unroll
      for (int t = 0; t < 4; ++t) {
        union { unsigned int i; float f; } lo, hi;
        lo.i = uu[t] << 16;
        hi.i = uu[t] & 0xffff0000u;
        s[q * 8 + t * 2] = lo.f;
        s[q * 8 + t * 2 + 1] = hi.f;
      }
    }
    // one-pass sum / sum-of-squares (masked)
    float suml = 0.f, sql = 0.f;
#pragma unroll
    for (int u = 0; u < 16; ++u)
      if ((vbits >> u) & 1) { suml += s[u]; sql += s[u] * s[u]; }
    wred_sum2(suml, sql);
    float mean = suml / cnteff;
    float sdata = sql - 2.f * mean * suml + cnt * mean * mean;
    float stdv = sqrtf(fmaxf(sdata, 0.f) / cnteff + 1e-10f);
    float inv = 1.f / (stdv + 0.0001f);

    float maxl = -1e9f;
#pragma unroll
    for (int u = 0; u < 16; ++u) {
      float zz = (s[u] - mean) * inv;
      int vv = (vbits >> u) & 1;
      zz = vv ? zz : 0.f;
      s[u] = zz;  // masked z
      if (vv && zz >= 0.f) maxl = fmaxf(maxl, zz);
    }
    float rowmax = wred_max(maxl);

    float e[16], el = 0.f;
#pragma unroll
    for (int u = 0; u < 16; ++u) {
      int vv = (vbits >> u) & 1, aa = (abits >> u) & 1;
      float ev = (vv && aa && (s[u] >= 0.f)) ? expf(s[u] - rowmax) : 0.f;
      e[u] = ev + 1e-10f;
      el += e[u];
    }
    float esum = wred_sum(el);
    float rinv = 1.f / esum;

    float wl = 0.f;
    unsigned int wo[8];
#pragma unroll
    for (int u = 0; u < 16; u += 2) {
      int s0 = ((vbits >> u) & 1) && ((abits >> u) & 1) && (s[u] >= 0.f);
      int s1 = ((vbits >> (u + 1)) & 1) && ((abits >> (u + 1)) & 1) && (s[u + 1] >= 0.f);
      float w0 = s0 ? e[u] * rinv : 0.f;
      float w1 = s1 ? e[u + 1] * rinv : 0.f;
      wl += w0 + w1;
      wo[u >> 1] = (unsigned)f2bf(w0) | ((unsigned)f2bf(w1) << 16);
    }
    float wsum = wred_sum(wl);

    u16* orow = wout + ((size_t)z << 20) + ((size_t)n << 10) + e0;
    reinterpret_cast<uint4*>(orow)[0] = make_uint4(wo[0], wo[1], wo[2], wo[3]);
    reinterpret_cast<uint4*>(orow)[1] = make_uint4(wo[4], wo[5], wo[6], wo[7]);
    if (lane == 0) denh[(z << 10) + n] = wsum + 1.0f;
  }
}

// ---- fused GCN layer: T = wght@srcT^T + src (regs) -> LDS -> out GEMM ------
__global__ __launch_bounds__(256) void gcn_k(
    const u16* __restrict__ wght, const u16* __restrict__ srcT,
    const u16* __restrict__ addsrc, int zmask, int ldadd, long long sAdd,
    const u16* __restrict__ WgT_all, const float* __restrict__ bg_all,
    const float* __restrict__ den, int l,
    u16* __restrict__ ob, u16* __restrict__ obT, u16* __restrict__ fin) {
  __shared__ u16 lds[35328];
  u16* As = lds;             // [64][72]  stage 1
  u16* Bs = lds + 4608;      // [256][72] stage 1
  u16* Ts = lds;             // [64][264] stage 2 (overwrites stage-1 area)
  u16* Ws = lds + 16896;     // [256][72] stage 2
  int tid = threadIdx.x;
  int m0 = blockIdx.x << 6;
  int z = blockIdx.y;
  int lane = tid & 63, w = tid >> 6;
  int lr = lane & 15, lq8 = (lane >> 4) << 3, lq4 = (lane >> 4) << 2;

  const u16* Aw = wght + ((long long)z << 20) + (long long)m0 * 1024;
  const u16* Bt = srcT + (long long)(z & zmask) * 262144;
  const u16* addb = addsrc + (long long)(z & zmask) * sAdd;
  int idx2 = (z >> 2) * 2 + l;
  const u16* Wg = WgT_all + (long long)idx2 * 65536;

  floatx4 acc[4][4] = {};
  // ---- stage 1: T tile 64x256, K=1024 ----
  for (int k0 = 0; k0 < 1024; k0 += 64) {
#pragma unroll
    for (int j = 0; j < 2; ++j) {
      int id = tid + (j << 8);
      int row = id >> 3, c8 = (id & 7) << 3;
      *reinterpret_cast<float4*>(As + row * 72 + c8) =
          *reinterpret_cast<const float4*>(Aw + (long long)row * 1024 + k0 + c8);
    }
#pragma unroll
    for (int j = 0; j < 8; ++j) {
      int id = tid + (j << 8);
      int row = id >> 3, c8 = (id & 7) << 3;
      *reinterpret_cast<float4*>(Bs + row * 72 + c8) =
          *reinterpret_cast<const float4*>(Bt + (long long)row * 1024 + k0 + c8);
    }
    __syncthreads();
#pragma unroll
    for (int kc = 0; kc < 64; kc += 32) {
      short8 a[4], b[4];
#pragma unroll
      for (int t = 0; t < 4; ++t) {
        a[t] = *reinterpret_cast<const short8*>(As + (t * 16 + lr) * 72 + kc + lq8);
        b[t] = *reinterpret_cast<const short8*>(Bs + ((w << 6) + t * 16 + lr) * 72 + kc + lq8);
      }
#pragma unroll
      for (int ti = 0; ti < 4; ++ti)
#pragma unroll
        for (int tj = 0; tj < 4; ++tj)
          acc[ti][tj] =
              __builtin_amdgcn_mfma_f32_16x16x32_bf16(a[ti], b[tj], acc[ti][tj], 0, 0, 0);
    }
    __syncthreads();
  }
  // ---- T (+src) -> LDS in A-operand layout; zero accs ----
#pragma unroll
  for (int ti = 0; ti < 4; ++ti)
#pragma unroll
    for (int tj = 0; tj < 4; ++tj)
#pragma unroll
      for (int r = 0; r < 4; ++r) {
        int row = ti * 16 + lq4 + r;
        int col = (w << 6) + tj * 16 + lr;
        float v = acc[ti][tj][r] + bf2f(addb[(long long)(m0 + row) * ldadd + col]);
        Ts[row * 264 + col] = f2bf(v);
        acc[ti][tj][r] = 0.f;
      }
  __syncthreads();
  // ---- stage 2: out = T @ Wg^T, K=256 ----
  for (int kc0 = 0; kc0 < 256; kc0 += 64) {
#pragma unroll
    for (int j = 0; j < 8; ++j) {
      int id = tid + (j << 8);
      int row = id >> 3, c8 = (id & 7) << 3;
      *reinterpret_cast<float4*>(Ws + row * 72 + c8) =
          *reinterpret_cast<const float4*>(Wg + (long long)row * 256 + kc0 + c8);
    }
    __syncthreads();
#pragma unroll
    for (int kc = 0; kc < 64; kc += 32) {
      short8 a[4], b[4];
#pragma unroll
      for (int t = 0; t < 4; ++t) {
        a[t] = *reinterpret_cast<const short8*>(Ts + (t * 16 + lr) * 264 + kc0 + kc + lq8);
        b[t] = *reinterpret_cast<const short8*>(Ws + ((w << 6) + t * 16 + lr) * 72 + kc + lq8);
      }
#pragma unroll
      for (int ti = 0; ti < 4; ++ti)
#pragma unroll
        for (int tj = 0; tj < 4; ++tj)
          acc[ti][tj] =
              __builtin_amdgcn_mfma_f32_16x16x32_bf16(a[ti], b[tj], acc[ti][tj], 0, 0, 0);
    }
    __syncthreads();
  }
  // ---- epilogue: relu((. + 2b)/den) -> fin slice (+ob row-major, obT K-major)
  const float* bb = bg_all + idx2 * 256;
  const float* dn = den + (z << 10);
  long long finbase = (long long)(z & 3) * 2097152 + idx2 * 256;
#pragma unroll
  for (int ti = 0; ti < 4; ++ti) {
    int row = m0 + ti * 16 + lq4;  // +r below; multiple of 4
#pragma unroll
    for (int tj = 0; tj < 4; ++tj) {
      int col = (w << 6) + tj * 16 + lr;
      u16 bv4[4];
#pragma unroll
      for (int r = 0; r < 4; ++r) {
        float v = (acc[ti][tj][r] + 2.f * bb[col]) / dn[row + r];
        v = fmaxf(v, 0.f);
        bv4[r] = f2bf(v);
        fin[finbase + (long long)(row + r) * 2048 + col] = bv4[r];
        if (ob) ob[((long long)z << 18) + (long long)(row + r) * 256 + col] = bv4[r];
      }
      if (obT) {
        ushort4 t4 = {bv4[0], bv4[1], bv4[2], bv4[3]};
        *reinterpret_cast<ushort4*>(obT + ((long long)z << 18) +
                                    (long long)col * 1024 + row) = t4;
      }
    }
  }
}

// ---- final split-K: out += fin @ Wo^T (atomic f32) -------------------------
__global__ __launch_bounds__(256) void mfinal_k(
    const u16* __restrict__ fin, const u16* __restrict__ WoT,
    float* __restrict__ out) {
  __shared__ u16 As[64 * LDS_P], Bs[64 * LDS_P];
  int m0 = blockIdx.y << 6, n0 = blockIdx.x << 6;
  int ks = blockIdx.z << 9;  // 4 splits of 512
  floatx4 acc[2][2] = {};
  mfma_loop(fin + (long long)m0 * 2048 + ks, 2048, WoT + (long long)n0 * 2048 + ks,
            2048, 512, As, Bs, acc, threadIdx.x);
  EPI_SETUP
#pragma unroll
  for (int ti = 0; ti < 2; ++ti)
#pragma unroll
    for (int tj = 0; tj < 2; ++tj)
#pragma unroll
      for (int r = 0; r < 4; ++r) {
        int row = m0 + wm + ti * 16 + lq4 + r;
        int col = n0 + wn + tj * 16 + lr;
        atomicAdd(out + (long long)row * 256 + col, acc[ti][tj][r]);
      }
}

// ---- one prep kernel: concat, transposes, bf16 casts, out init -------------
__global__ __launch_bounds__(256) void prep_k(
    const float* __restrict__ X, const float* __restrict__ R,
    const float* __restrict__ W_Q, const float* __restrict__ W_K,
    const float* __restrict__ W_gcn, const float* __restrict__ W_out,
    const float* __restrict__ b_out,
    u16* __restrict__ A, u16* __restrict__ XT, u16* __restrict__ WQT,
    u16* __restrict__ WKT, u16* __restrict__ WgT, u16* __restrict__ WoT,
    float* __restrict__ out) {
  int gid = blockIdx.x * 256 + threadIdx.x;
  if (gid < 2097152) {  // A = [X|R] bf16
    int col = gid & 511, row = gid >> 9;
    float v = (col < 256) ? X[row * 256 + col] : R[row * 256 + col - 256];
    A[gid] = f2bf(v);
  } else if (gid < 3145728) {  // XT
    int t = gid - 2097152;
    int b = t >> 18, r2 = t & 262143;
    int i = r2 >> 8, j = r2 & 255;
    XT[b * 262144 + j * 1024 + i] = f2bf(X[t]);
  } else if (gid < 3276800) {  // WQT
    int t = gid - 3145728;
    int i = t >> 8, j = t & 255;
    WQT[j * 512 + i] = f2bf(W_Q[t]);
  } else if (gid < 3342336) {  // WKT
    int t = gid - 3276800;
    int i = t >> 8, j = t & 255;
    WKT[j * 256 + i] = f2bf(W_K[t]);
  } else if (gid < 3866624) {  // WgT
    int t = gid - 3342336;
    int zz = t >> 16, r2 = t & 65535;
    int i = r2 >> 8, j = r2 & 255;
    WgT[zz * 65536 + j * 256 + i] = f2bf(W_gcn[t]);
  } else if (gid < 4390912) {  // WoT
    int t = gid - 3866624;
    int i = t >> 8, j = t & 255;
    WoT[j * 2048 + i] = f2bf(W_out[t]);
  } else if (gid < 4653056) {  // out = X + b_out (float4 units)
    int t = gid - 4390912;
    int col = (t << 2) & 255;
    float4 x = reinterpret_cast<const float4*>(X)[t];
    float4 b = *reinterpret_cast<const float4*>(b_out + col);
    x.x += b.x; x.y += b.y; x.z += b.z; x.w += b.w;
    reinterpret_cast<float4*>(out)[t] = x;
  }
}

// ---- launch ----------------------------------------------------------------
extern "C" void kernel_launch(void* const* d_in, const int* in_sizes, int n_in,
                              void* d_out, int out_size, void* d_ws, size_t ws_size,
                              hipStream_t stream) {
  const float* X = (const float*)d_in[0];
  const float* R = (const float*)d_in[1];
  const int* adj = (const int*)d_in[2];
  const int* mask = (const int*)d_in[3];
  const float* W_Q = (const float*)d_in[4];
  const float* b_Q = (const float*)d_in[5];
  const float* W_K = (const float*)d_in[6];
  const float* b_K = (const float*)d_in[7];
  const float* W_gcn = (const float*)d_in[8];
  const float* b_gcn = (const float*)d_in[9];
  const float* W_out = (const float*)d_in[10];
  const float* b_out = (const float*)d_in[11];
  float* out = (float*)d_out;

  u16* wsu = (u16*)d_ws;
  u16* A_qk = wsu;                        // [4096][512]      2M u16
  u16* qbf  = A_qk + (2u << 20);          // [4096][256]      1M
  u16* kbf  = qbf + (1u << 20);           // [4096][256]      1M
  u16* XT   = kbf + (1u << 20);           // [4][256][1024]   1M
  u16* WQT  = XT + (1u << 20);            // [256][512]       128K
  u16* WKT  = WQT + (1u << 17);           // [256][256]       64K
  u16* WgT  = WKT + (1u << 16);           // [8][256][256]    512K
  u16* WoT  = WgT + (1u << 19);           // [256][2048]      512K
  u16* ob   = WoT + (1u << 19);           // [16][1024][256]  4M
  u16* obT  = ob + (4u << 20);            // [16][256][1024]  4M
  u16* finb = obT + (4u << 20);           // [4][1024][2048]  8M
  u16* wght = finb + (8u << 20);          // [16][1024][1024] 16M
  float* den = (float*)(wght + (16u << 20));   // [16][1024] f32
  u16* sc = (u16*)(den + (1 << 14));           // [16][1024][1024] bf16 (32 MB)

  // prep (concat, transposes, casts, out init) — one launch
  prep_k<<<18176, 256, 0, stream>>>(X, R, W_Q, W_K, W_gcn, W_out, b_out,
                                    A_qk, XT, WQT, WKT, WgT, WoT, out);

  // q & k projections (one launch)
  proj2_k<<<dim3(4, 64, 2), 256, 0, stream>>>(A_qk, WQT, WKT, b_Q, b_K, qbf, kbf);

  // scores (all 16 slices, bf16) + z-score chain (wave-per-row, no barriers)
  mscore_k<<<dim3(16, 16, 16), 256, 0, stream>>>(qbf, kbf, sc);
  zscore_w<<<1024, 256, 0, stream>>>(sc, adj, mask, wght, den);

  // fused GCN layers (layer 0 also emits obT for layer 1's K-major operand)
  gcn_k<<<dim3(16, 16), 256, 0, stream>>>(wght, XT, A_qk, 3, 512, 524288LL,
                                          WgT, b_gcn, den, 0, ob, obT, finb);
  gcn_k<<<dim3(16, 16), 256, 0, stream>>>(wght, obT, ob, 15, 256, 262144LL,
                                          WgT, b_gcn, den, 1, nullptr, nullptr, finb);

  // final split-K accumulate
  mfinal_k<<<dim3(4, 64, 4), 256, 0, stream>>>(finb, WoT, out);
}